// Round 7
// baseline (244.976 us; speedup 1.0000x reference)
//
#include <hip/hip_runtime.h>
#include <math.h>

#define B_ 32
#define Q_ 1024
#define G_ 64
#define K16 16   // columns per lane in matcher (Q_ / 64)

typedef double v16d __attribute__((ext_vector_type(16)));
typedef float  v16f __attribute__((ext_vector_type(16)));
typedef int    v16i __attribute__((ext_vector_type(16)));

// X-macro: OP(K, H) with K = int index, H = hex element suffix
#define REP16(OP) OP(0,0) OP(1,1) OP(2,2) OP(3,3) OP(4,4) OP(5,5) OP(6,6) OP(7,7) \
                  OP(8,8) OP(9,9) OP(10,a) OP(11,b) OP(12,c) OP(13,d) OP(14,e) OP(15,f)
#define REP16A(OP,A) OP(A,0,0) OP(A,1,1) OP(A,2,2) OP(A,3,3) OP(A,4,4) OP(A,5,5) OP(A,6,6) OP(A,7,7) \
                     OP(A,8,8) OP(A,9,9) OP(A,10,a) OP(A,11,b) OP(A,12,c) OP(A,13,d) OP(A,14,e) OP(A,15,f)

// ---- cross-lane helpers -------------------------------------------------
#define ROR1 0x121
#define ROR2 0x122
#define ROR4 0x124
#define ROR8 0x128
#define BC15 0x142
#define BC31 0x143

template<int CTRL>
__device__ __forceinline__ double dpp_f64(double x) {
    union { double d; int i[2]; } a; a.d = x;
    union { int i[2]; double d; } r;
    r.i[0] = __builtin_amdgcn_update_dpp(a.i[0], a.i[0], CTRL, 0xF, 0xF, false);
    r.i[1] = __builtin_amdgcn_update_dpp(a.i[1], a.i[1], CTRL, 0xF, 0xF, false);
    return r.d;
}
template<int CTRL>
__device__ __forceinline__ int dpp_i32(int x) {
    return __builtin_amdgcn_update_dpp(x, x, CTRL, 0xF, 0xF, false);
}

__device__ __forceinline__ double readlane_f64(double x, int sl) {
    const int s = __builtin_amdgcn_readfirstlane(sl);
    union { double d; int i2[2]; } a; a.d = x;
    union { int i2[2]; double d; } r;
    r.i2[0] = __builtin_amdgcn_readlane(a.i2[0], s);
    r.i2[1] = __builtin_amdgcn_readlane(a.i2[1], s);
    return r.d;
}
__device__ __forceinline__ double readlane_f64c(double x, int sl) {  // const lane
    union { double d; int i2[2]; } a; a.d = x;
    union { int i2[2]; double d; } r;
    r.i2[0] = __builtin_amdgcn_readlane(a.i2[0], sl);
    r.i2[1] = __builtin_amdgcn_readlane(a.i2[1], sl);
    return r.d;
}
__device__ __forceinline__ float readlane_f32u(float x, int sl) {
    union { float f; int i; } a; a.f = x;
    union { int i; float f; } r;
    r.i = __builtin_amdgcn_readlane(a.i, __builtin_amdgcn_readfirstlane(sl));
    return r.f;
}
__device__ __forceinline__ int readlane_i32(int x, int sl) {
    return __builtin_amdgcn_readlane(x, __builtin_amdgcn_readfirstlane(sl));
}
__device__ __forceinline__ int readlane_i32c(int x, int sl) {
    return __builtin_amdgcn_readlane(x, sl);
}

// tree-select element s (uniform, 0..15) of a v16i held in registers
__device__ __forceinline__ int sel16v_i(v16i p, int s) {
    const int t0_0 = (s & 1) ? p.s1 : p.s0;
    const int t0_1 = (s & 1) ? p.s3 : p.s2;
    const int t0_2 = (s & 1) ? p.s5 : p.s4;
    const int t0_3 = (s & 1) ? p.s7 : p.s6;
    const int t0_4 = (s & 1) ? p.s9 : p.s8;
    const int t0_5 = (s & 1) ? p.sb : p.sa;
    const int t0_6 = (s & 1) ? p.sd : p.sc;
    const int t0_7 = (s & 1) ? p.sf : p.se;
    const int t1_0 = (s & 2) ? t0_1 : t0_0;
    const int t1_1 = (s & 2) ? t0_3 : t0_2;
    const int t1_2 = (s & 2) ? t0_5 : t0_4;
    const int t1_3 = (s & 2) ? t0_7 : t0_6;
    const int a0 = (s & 4) ? t1_1 : t1_0;
    const int a1 = (s & 4) ? t1_3 : t1_2;
    return (s & 8) ? a1 : a0;
}
__device__ __forceinline__ double sel16v_d(v16d p, int s) {
    const double t0_0 = (s & 1) ? p.s1 : p.s0;
    const double t0_1 = (s & 1) ? p.s3 : p.s2;
    const double t0_2 = (s & 1) ? p.s5 : p.s4;
    const double t0_3 = (s & 1) ? p.s7 : p.s6;
    const double t0_4 = (s & 1) ? p.s9 : p.s8;
    const double t0_5 = (s & 1) ? p.sb : p.sa;
    const double t0_6 = (s & 1) ? p.sd : p.sc;
    const double t0_7 = (s & 1) ? p.sf : p.se;
    const double t1_0 = (s & 2) ? t0_1 : t0_0;
    const double t1_1 = (s & 2) ? t0_3 : t0_2;
    const double t1_2 = (s & 2) ? t0_5 : t0_4;
    const double t1_3 = (s & 2) ? t0_7 : t0_6;
    const double a0 = (s & 4) ? t1_1 : t1_0;
    const double a1 = (s & 4) ? t1_3 : t1_2;
    return (s & 8) ? a1 : a0;
}

// Fused (value, index) min over 16 cand/lane x 64 lanes; ties -> smallest
// j = (k<<6)|l (np.argmin first-occurrence). ROUND-3 form (measured fastest):
// fmin TREE (depth 4, ILP) -> value-only f64 DPP min -> binary walk down the
// stored partials for the local smallest-k -> i32 key min-DPP for the global
// smallest-j.
__device__ __forceinline__ void lexpair(v16d c, int l,
                                        double& gv_o, int& jm_o) {
    const double a0 = fmin(c.s0, c.s1), a1 = fmin(c.s2, c.s3),
                 a2 = fmin(c.s4, c.s5), a3 = fmin(c.s6, c.s7),
                 a4 = fmin(c.s8, c.s9), a5 = fmin(c.sa, c.sb),
                 a6 = fmin(c.sc, c.sd), a7 = fmin(c.se, c.sf);
    const double b0 = fmin(a0, a1), b1 = fmin(a2, a3),
                 b2 = fmin(a4, a5), b3 = fmin(a6, a7);
    const double d0 = fmin(b0, b1), d1 = fmin(b2, b3);
    const double vloc = fmin(d0, d1);
    double v = vloc;
#define VS_(C) { const double pv = dpp_f64<C>(v); v = fmin(pv, v); }
    VS_(ROR1) VS_(ROR2) VS_(ROR4) VS_(ROR8) VS_(BC15) VS_(BC31)
#undef VS_
    const double gv = readlane_f64c(v, 63);
    const int bit3 = (d0 == gv) ? 0 : 1;
    const double bsel = bit3 ? b2 : b0;
    const int bit2 = (bsel == gv) ? 0 : 1;
    const double asel = bit2 ? (bit3 ? a6 : a2) : (bit3 ? a4 : a0);
    const int bit1 = (asel == gv) ? 0 : 1;
    const double csel = bit1 ? (bit2 ? (bit3 ? c.se : c.s6) : (bit3 ? c.sa : c.s2))
                             : (bit2 ? (bit3 ? c.sc : c.s4) : (bit3 ? c.s8 : c.s0));
    const int bit0 = (csel == gv) ? 0 : 1;
    const int kloc = (bit3 << 3) | (bit2 << 2) | (bit1 << 1) | bit0;
    int key = (vloc == gv) ? ((kloc << 6) | l) : 0x7FFFFFFF;
#define KS_(C) { const int pk = dpp_i32<C>(key); key = (pk < key) ? pk : key; }
    KS_(ROR1) KS_(ROR2) KS_(ROR4) KS_(ROR8) KS_(BC15) KS_(BC31)
#undef KS_
    jm_o = readlane_i32c(key, 63);
    gv_o = gv;
}

// ---- matcher core (round-3 verified logic, loader-templated) -------------
// LDS-free JV matcher on one wave. See earlier rounds for invariants/proofs.
// All per-lane state in ext_vectors with compile-time element access: NO
// alloca may exist (round-1 lesson: promote-alloca-to-LDS cost 40us).
template<class LR>
__device__ __forceinline__ void matcher_core(
    const int l, const int g, LR load_row,
    const float pre_v, const int pre_j, const float sec_v, const int sec_j,
    float* __restrict__ out_ind_b, float* __restrict__ out_mask_b)
{
    const double INF = __builtin_inf();
    double u_rep = 0.0;       // u[l]
    double m_rec = 0.0;       // minv at the pop that added row l to SR
    bool   inSR  = false;
    int    c4r_rep = -1;      // col4row[l]
    unsigned asg   = 0u;      // bit k: column l+64k assigned (output only)
    unsigned dirty = 0u;      // bit k: v of column l+64k STRICTLY changed
    v16d v_r, sh_r;
    v16i path;
    v16f c_cur, c_i;
#define INI_(K,H) { v_r.s##H = 0.0; sh_r.s##H = 0.0; path.s##H = 0; }
    REP16(INI_)
#undef INI_
#define Z16_(K,H) { c_cur.s##H = 0.0f; c_i.s##H = 0.0f; }
    REP16(Z16_)
#undef Z16_

    for (int cur = 0; cur < g; ++cur) {
        // ---- step-1 argmin ----
        const float pre_vc = readlane_f32u(pre_v, cur);
        int jm = readlane_i32(pre_j, cur);
        double minv = (double)pre_vc;
        bool have_cur = false;
        {
            const int ow1 = jm & 63, sl1 = jm >> 6;
            const unsigned d1 = (unsigned)readlane_i32((int)dirty, ow1);
            if ((d1 >> sl1) & 1u) {
                // best column dirty -> try exact second-best resolution
                const float sv_c = readlane_f32u(sec_v, cur);
                const int   sj_c = readlane_i32(sec_j, cur);
                const unsigned d2 = (unsigned)readlane_i32((int)dirty, sj_c & 63);
                if (!((d2 >> (sj_c >> 6)) & 1u) && (sj_c != jm)) {
                    const double vpj = readlane_f64(sel16v_d(v_r, sl1), ow1);
                    const double vA = (double)pre_vc - vpj;   // exact: (f64)cost - v
                    const double vB = (double)sv_c;           // clean: v == 0
                    const bool tt = (vB < vA) || ((vB == vA) && (sj_c < jm));
                    minv = tt ? vB : vA;
                    jm   = tt ? sj_c : jm;
                } else {
                    c_cur = load_row(cur); have_cur = true;
                    v16d rr0;
#define RR0_(K,H) rr0.s##H = (double)c_cur.s##H - v_r.s##H;
                    REP16(RR0_)
#undef RR0_
                    lexpair(rr0, l, minv, jm);
                }
            }
        }
        const unsigned long long mk0 = __ballot(c4r_rep == jm);

        if (mk0 == 0ull) {
            // ---- fast row: O(1) bookkeeping (u,v of others unchanged) ----
            u_rep   = (l == cur) ? u_rep + minv : u_rep;
            c4r_rep = (l == cur) ? jm           : c4r_rep;
            asg     = (l == (jm & 63)) ? (asg | (1u << (jm >> 6))) : asg;
        } else {
            // ---- slow path: exact reference Dijkstra from step-1 state ----
            if (!have_cur) c_cur = load_row(cur);
            int i = (int)__builtin_ctzll(mk0);
            c_i = load_row(i);
            double ui = readlane_f64(u_rep, i);
            unsigned sc = (l == (jm & 63)) ? (1u << (jm >> 6)) : 0u;
            inSR  = (l == i);
            m_rec = minv;                            // valid only where inSR
#define SH0_(K,H) { sh_r.s##H = (double)c_cur.s##H - v_r.s##H; path.s##H = cur; }
            REP16(SH0_)
#undef SH0_

            int sink = -1;
            while (sink < 0) {
                v16d cand;
#define DST_(K,H) { const double rr = ((minv + (double)c_i.s##H) - ui) - v_r.s##H; \
                    const bool notSC = !((sc >> K) & 1u); \
                    const bool upd = notSC && (rr < sh_r.s##H); /* strict < */ \
                    sh_r.s##H = upd ? rr : sh_r.s##H; \
                    path.s##H = upd ? i : path.s##H; \
                    cand.s##H = notSC ? sh_r.s##H : INF; }
                REP16(DST_)
#undef DST_
                lexpair(cand, l, minv, jm);
                const unsigned long long mk = __ballot(c4r_rep == jm);
                if (l == (jm & 63)) sc |= (1u << (jm >> 6));
                if (mk == 0ull) {
                    sink = jm;
                } else {
                    i = (int)__builtin_ctzll(mk);
                    c_i = load_row(i);
                    if (l == i) { inSR = true; m_rec = minv; }
                    ui = readlane_f64(u_rep, i);
                }
            }

            // dual updates (reference order: u, then v, then augment).
            if (l == cur)       u_rep += minv;
            else if (inSR)      u_rep += minv - m_rec;
            unsigned chg = 0u;
#define VUP_(K,H) { const bool in_sc = (sc >> K) & 1u; \
                    const double nv = v_r.s##H - (minv - sh_r.s##H); \
                    chg = (in_sc && (sh_r.s##H != minv)) ? (chg | (1u << K)) : chg; \
                    v_r.s##H = in_sc ? nv : v_r.s##H; }
            REP16(VUP_)
#undef VUP_
            dirty |= chg;   // EXACT: only strictly-changed columns

            // augment along alternating path
            int j = sink;
            while (true) {
                const int so = j & 63, ss = j >> 6;
                const int ii = readlane_i32(sel16v_i(path, ss), so);
                const int nj = readlane_i32(c4r_rep, ii);   // old col4row[ii]
                asg     = (l == so) ? (asg | (1u << ss)) : asg;
                c4r_rep = (l == ii) ? j : c4r_rep;
                j = nj;
                if (ii == cur) break;
            }
        }
    }

    // ---- output: mask/zeros from asg bits; indices via one scatter ----
#define OUT_(K,H) { const int jj = l + (K << 6); const bool a_ = (asg >> K) & 1u; \
    out_mask_b[jj] = a_ ? 1.0f : 0.0f; \
    if (!a_) out_ind_b[jj] = 0.0f; }
    REP16(OUT_)
#undef OUT_
    if (c4r_rep >= 0) out_ind_b[c4r_rep] = (float)l;  // disjoint from zeros
}

// ---- ONE launch, two roles (544 blocks x 256 threads) --------------------
// Blocks 32..543: build (512-way parallel, identical arithmetic/outputs to
// the old build_kernel). Blocks 0..31: matcher for batch b = blockIdx.x,
// gated on flags[b] reaching 16 (release-add by each of b's chunk blocks;
// acquire-spin by the matcher). Removes the ~15us inter-kernel launch gap
// (R4 vs two-kernel "rest" delta) WITHOUT serializing the build (R4's bug).
// Residency: __launch_bounds__(256,4) caps VGPR at 128 -> 4 blocks/CU ->
// 1024 slots >= 544, so spinning blocks cannot starve build blocks.
// Mapping: batch == blockIdx (mod 8) for both roles (XCD-aligned, free).
__global__ __launch_bounds__(256, 4) void fused2_k(
    const float* __restrict__ obj, const float* __restrict__ cd,
    const float* __restrict__ gi, const int* __restrict__ ngt,
    float* __restrict__ ct,
    float* __restrict__ pv, int* __restrict__ pj,
    float* __restrict__ pv2, int* __restrict__ pj2,
    unsigned* __restrict__ flags,
    float* __restrict__ out_ind, float* __restrict__ out_mask)
{
    __shared__ float tile[64][65];
    const int t   = threadIdx.x;
    const int bid = blockIdx.x;

    if (bid >= B_) {
        // ================= build role =================
        const int n0 = bid - B_;
        const int b  = (n0 & 7) + (((n0 >> 3) & 3) << 3);   // batch (== bid mod 8)
        const int cb = n0 >> 5;                             // column chunk 0..15
        const int jb = cb << 6;
        const float* objb = obj + (b << 10);
        const float4* cd4 = (const float4*)(cd + ((size_t)b << 16));
        const float4* gi4 = (const float4*)(gi + ((size_t)b << 16));

        #pragma unroll
        for (int p = 0; p < 4; ++p) {
            const int f  = t + (p << 8);
            const int jj = f >> 4;          // 0..63
            const int q  = f & 15;
            const int i0 = q << 2;          // 0,4,..,60
            const int j  = jb + jj;
            const float om = __fmul_rn(5.0f, -objb[j]);
            const float4 c4 = cd4[(j << 4) + q];
            const float4 q4 = gi4[(j << 4) + q];
            tile[i0 + 0][jj] = __fadd_rn(__fadd_rn(om, __fmul_rn(10.0f, c4.x)), __fmul_rn(2.0f, -q4.x));
            tile[i0 + 1][jj] = __fadd_rn(__fadd_rn(om, __fmul_rn(10.0f, c4.y)), __fmul_rn(2.0f, -q4.y));
            tile[i0 + 2][jj] = __fadd_rn(__fadd_rn(om, __fmul_rn(10.0f, c4.z)), __fmul_rn(2.0f, -q4.z));
            tile[i0 + 3][jj] = __fadd_rn(__fadd_rn(om, __fmul_rn(10.0f, c4.w)), __fmul_rn(2.0f, -q4.w));
        }
        __syncthreads();
        #pragma unroll
        for (int r = 0; r < 16; ++r) {      // coalesced ct write
            const int idx = (r << 8) + t;
            const int i = idx >> 6, j2 = idx & 63;
            ct[(((size_t)(b << 6) + i) << 10) + jb + j2] = tile[i][j2];
        }
        if (t < 64) {                        // (best, second) for row t
            float bv = tile[t][0]; int bc = 0;
            float sv = 1e30f;      int sc2 = 0;
            #pragma unroll 8
            for (int c = 1; c < 64; ++c) {
                const float v = tile[t][c];
                const bool t1 = v < bv;                 // strict: first occurrence
                const bool t2 = (!t1) && (v < sv);
                sv  = t1 ? bv : (t2 ? v : sv);
                sc2 = t1 ? bc : (t2 ? c : sc2);
                bv  = t1 ? v : bv;
                bc  = t1 ? c : bc;
            }
            const int o = (((b << 6) + t) << 4) + cb;
            pv[o]  = bv;  pj[o]  = jb + bc;
            pv2[o] = sv;  pj2[o] = jb + sc2;
        }
        __syncthreads();   // all this block's stores drained to L2 (vmcnt0)
        if (t == 0)        // publish: device-scope release add
            __hip_atomic_fetch_add(&flags[b], 1u, __ATOMIC_RELEASE,
                                   __HIP_MEMORY_SCOPE_AGENT);
        return;
    }

    // ================= matcher role =================
    const int b = bid;
    if (t == 0) {          // acquire-spin until this batch's 16 chunks done
        while (__hip_atomic_load(&flags[b], __ATOMIC_ACQUIRE,
                                 __HIP_MEMORY_SCOPE_AGENT) < 16u)
            __builtin_amdgcn_s_sleep(2);
    }
    __syncthreads();       // whole block ordered behind the acquire

    const float* ctb = ct + ((size_t)(b << 6) << 10);
    if (t >= 64) {
        // ---- L2-warm waves (round-6, +7.5us): pull the 256KB slice from
        // LLC into this XCD's L2; DCE-protected reads, then retire. ----
        const float4* c4p = (const float4*)ctb;     // 16384 float4 per batch
        for (int n = t - 64; n < 16384; n += 192) {
            const float4 x = c4p[n];
            asm volatile("" :: "v"(x.x), "v"(x.y), "v"(x.z), "v"(x.w));
        }
        return;
    }

    const int l = t;
    const int g = ngt[b];

    // ---- per-row precomputed (best, second) -> lane l = row l ----
    const int base = ((b << 6) + l) << 4;
    const float4* pvq = (const float4*)(pv  + base);
    const int4*   pjq = (const int4*)(pj  + base);
    const float4* svq = (const float4*)(pv2 + base);
    const int4*   sjq = (const int4*)(pj2 + base);
    const float4 pA = pvq[0], pB = pvq[1], pC = pvq[2], pD = pvq[3];
    const int4   jA = pjq[0], jB = pjq[1], jC = pjq[2], jD = pjq[3];
    const float4 sA = svq[0], sB = svq[1], sC = svq[2], sD = svq[3];
    const int4   tA = sjq[0], tB = sjq[1], tC = sjq[2], tD = sjq[3];
    float bv = pA.x; int bj = jA.x; float sv = sA.x; int sj = tA.x;
    // merge chunks ascending; (best, second) both first-occurrence exact
#define MERGE_(CV,CJ,C2V,C2J) { const bool nb = (CV) < bv; \
    const bool s1 = (C2V) < bv; const bool s2 = (CV) < sv; \
    const float nsv = nb ? (s1 ? (C2V) : bv) : (s2 ? (CV) : sv); \
    const int   nsj = nb ? (s1 ? (C2J) : bj) : (s2 ? (CJ) : sj); \
    bj = nb ? (CJ) : bj; bv = nb ? (CV) : bv; sv = nsv; sj = nsj; }
    MERGE_(pA.y,jA.y,sA.y,tA.y) MERGE_(pA.z,jA.z,sA.z,tA.z) MERGE_(pA.w,jA.w,sA.w,tA.w)
    MERGE_(pB.x,jB.x,sB.x,tB.x) MERGE_(pB.y,jB.y,sB.y,tB.y) MERGE_(pB.z,jB.z,sB.z,tB.z) MERGE_(pB.w,jB.w,sB.w,tB.w)
    MERGE_(pC.x,jC.x,sC.x,tC.x) MERGE_(pC.y,jC.y,sC.y,tC.y) MERGE_(pC.z,jC.z,sC.z,tC.z) MERGE_(pC.w,jC.w,sC.w,tC.w)
    MERGE_(pD.x,jD.x,sD.x,tD.x) MERGE_(pD.y,jD.y,sD.y,tD.y) MERGE_(pD.z,jD.z,sD.z,tD.z) MERGE_(pD.w,jD.w,sD.w,tD.w)
#undef MERGE_

    auto load_row = [&](int ri) -> v16f {
        v16f d; const float* rp_ = ctb + ((size_t)ri << 10) + l;
#define LDW_(D,K,H) D.s##H = rp_[(K) << 6];
        REP16A(LDW_, d)
#undef LDW_
        return d;
    };
    matcher_core(l, g, load_row, bv, bj, sv, sj,
                 out_ind + (b << 10), out_mask + (b << 10));
}

// ---- no-workspace fallback: compute rows on the fly ----------------------
__global__ __launch_bounds__(64, 1) void matcher_nws(
    const float* __restrict__ obj, const float* __restrict__ cd,
    const float* __restrict__ gi, const int* __restrict__ ngt,
    float* __restrict__ out_ind, float* __restrict__ out_mask)
{
    const int b = blockIdx.x;
    const int l = threadIdx.x;
    const int g = ngt[b];
    const float* objb = obj + (b << 10);
    const float* cdb  = cd + ((size_t)b << 16);
    const float* gib  = gi + ((size_t)b << 16);

    v16f objm;
#define OBJI_(K,H) objm.s##H = __fmul_rn(5.0f, -objb[l + (K << 6)]);
    REP16(OBJI_)
#undef OBJI_
    auto load_row = [&](int ri) -> v16f {
        v16f d;
#define LDN_(D,K,H) { const int idx_ = ((l + ((K) << 6)) << 6) + ri; \
    D.s##H = __fadd_rn(__fadd_rn(objm.s##H, __fmul_rn(10.0f, cdb[idx_])), \
                       __fmul_rn(2.0f, -gib[idx_])); }
        REP16A(LDN_, d)
#undef LDN_
        return d;
    };

    float pre_v = 0.0f; int pre_j = 0;
    for (int i = 0; i < g; ++i) {            // cooperative per-row argmin
        v16f c = load_row(i);
        v16d c64;
#define CV_(K,H) c64.s##H = (double)c.s##H;
        REP16(CV_)
#undef CV_
        double gv; int j0;
        lexpair(c64, l, gv, j0);
        pre_v = (l == i) ? (float)gv : pre_v;
        pre_j = (l == i) ? j0 : pre_j;
    }
    // sec == pre: dirty best -> sec also dirty (same col) -> full recompute
    matcher_core(l, g, load_row, pre_v, pre_j, pre_v, pre_j,
                 out_ind + (b << 10), out_mask + (b << 10));
}

extern "C" void kernel_launch(void* const* d_in, const int* in_sizes, int n_in,
                              void* d_out, int out_size, void* d_ws, size_t ws_size,
                              hipStream_t stream)
{
    const float* obj = (const float*)d_in[1];
    const float* cd  = (const float*)d_in[2];
    const float* gi  = (const float*)d_in[3];
    const int*   ngt = (const int*)d_in[4];
    float* out0 = (float*)d_out;
    float* out1 = out0 + B_ * Q_;

    const size_t ct_b = (size_t)B_ * G_ * Q_ * sizeof(float);       // 8 MB
    const size_t pv_b = (size_t)B_ * G_ * 16 * sizeof(float);       // 128 KB
    const size_t fl_b = B_ * sizeof(unsigned);                      // 128 B
    if (ws_size >= ct_b + 4 * pv_b + fl_b) {
        float*    ct    = (float*)d_ws;
        float*    pv    = (float*)((char*)d_ws + ct_b);
        int*      pj    = (int*)  ((char*)d_ws + ct_b + pv_b);
        float*    pv2   = (float*)((char*)d_ws + ct_b + 2 * pv_b);
        int*      pj2   = (int*)  ((char*)d_ws + ct_b + 3 * pv_b);
        unsigned* flags = (unsigned*)((char*)d_ws + ct_b + 4 * pv_b);
        hipMemsetAsync(flags, 0, fl_b, stream);
        fused2_k<<<B_ + 16 * B_, 256, 0, stream>>>(obj, cd, gi, ngt, ct,
                                                   pv, pj, pv2, pj2, flags,
                                                   out0, out1);
    } else {
        matcher_nws<<<B_, 64, 0, stream>>>(obj, cd, gi, ngt, out0, out1);
    }
}

// Round 9
// 175.163 us; speedup vs baseline: 1.3986x; 1.3986x over previous
//
#include <hip/hip_runtime.h>
#include <math.h>

#define B_ 32
#define Q_ 1024
#define G_ 64
#define K16 16   // columns per lane in matcher (Q_ / 64)

typedef double v16d __attribute__((ext_vector_type(16)));
typedef float  v16f __attribute__((ext_vector_type(16)));
typedef int    v16i __attribute__((ext_vector_type(16)));

// X-macro: OP(K, H) with K = int index, H = hex element suffix
#define REP16(OP) OP(0,0) OP(1,1) OP(2,2) OP(3,3) OP(4,4) OP(5,5) OP(6,6) OP(7,7) \
                  OP(8,8) OP(9,9) OP(10,a) OP(11,b) OP(12,c) OP(13,d) OP(14,e) OP(15,f)
#define REP16A(OP,A) OP(A,0,0) OP(A,1,1) OP(A,2,2) OP(A,3,3) OP(A,4,4) OP(A,5,5) OP(A,6,6) OP(A,7,7) \
                     OP(A,8,8) OP(A,9,9) OP(A,10,a) OP(A,11,b) OP(A,12,c) OP(A,13,d) OP(A,14,e) OP(A,15,f)

// ---- cross-lane helpers -------------------------------------------------
#define ROR1 0x121
#define ROR2 0x122
#define ROR4 0x124
#define ROR8 0x128
#define BC15 0x142
#define BC31 0x143

template<int CTRL>
__device__ __forceinline__ double dpp_f64(double x) {
    union { double d; int i[2]; } a; a.d = x;
    union { int i[2]; double d; } r;
    r.i[0] = __builtin_amdgcn_update_dpp(a.i[0], a.i[0], CTRL, 0xF, 0xF, false);
    r.i[1] = __builtin_amdgcn_update_dpp(a.i[1], a.i[1], CTRL, 0xF, 0xF, false);
    return r.d;
}
template<int CTRL>
__device__ __forceinline__ int dpp_i32(int x) {
    return __builtin_amdgcn_update_dpp(x, x, CTRL, 0xF, 0xF, false);
}

__device__ __forceinline__ double readlane_f64(double x, int sl) {
    const int s = __builtin_amdgcn_readfirstlane(sl);
    union { double d; int i2[2]; } a; a.d = x;
    union { int i2[2]; double d; } r;
    r.i2[0] = __builtin_amdgcn_readlane(a.i2[0], s);
    r.i2[1] = __builtin_amdgcn_readlane(a.i2[1], s);
    return r.d;
}
__device__ __forceinline__ double readlane_f64c(double x, int sl) {  // const lane
    union { double d; int i2[2]; } a; a.d = x;
    union { int i2[2]; double d; } r;
    r.i2[0] = __builtin_amdgcn_readlane(a.i2[0], sl);
    r.i2[1] = __builtin_amdgcn_readlane(a.i2[1], sl);
    return r.d;
}
__device__ __forceinline__ float readlane_f32u(float x, int sl) {
    union { float f; int i; } a; a.f = x;
    union { int i; float f; } r;
    r.i = __builtin_amdgcn_readlane(a.i, __builtin_amdgcn_readfirstlane(sl));
    return r.f;
}
__device__ __forceinline__ int readlane_i32(int x, int sl) {
    return __builtin_amdgcn_readlane(x, __builtin_amdgcn_readfirstlane(sl));
}
__device__ __forceinline__ int readlane_i32c(int x, int sl) {
    return __builtin_amdgcn_readlane(x, sl);
}

// tree-select element s (uniform, 0..15) of a v16i held in registers
__device__ __forceinline__ int sel16v_i(v16i p, int s) {
    const int t0_0 = (s & 1) ? p.s1 : p.s0;
    const int t0_1 = (s & 1) ? p.s3 : p.s2;
    const int t0_2 = (s & 1) ? p.s5 : p.s4;
    const int t0_3 = (s & 1) ? p.s7 : p.s6;
    const int t0_4 = (s & 1) ? p.s9 : p.s8;
    const int t0_5 = (s & 1) ? p.sb : p.sa;
    const int t0_6 = (s & 1) ? p.sd : p.sc;
    const int t0_7 = (s & 1) ? p.sf : p.se;
    const int t1_0 = (s & 2) ? t0_1 : t0_0;
    const int t1_1 = (s & 2) ? t0_3 : t0_2;
    const int t1_2 = (s & 2) ? t0_5 : t0_4;
    const int t1_3 = (s & 2) ? t0_7 : t0_6;
    const int a0 = (s & 4) ? t1_1 : t1_0;
    const int a1 = (s & 4) ? t1_3 : t1_2;
    return (s & 8) ? a1 : a0;
}
__device__ __forceinline__ double sel16v_d(v16d p, int s) {
    const double t0_0 = (s & 1) ? p.s1 : p.s0;
    const double t0_1 = (s & 1) ? p.s3 : p.s2;
    const double t0_2 = (s & 1) ? p.s5 : p.s4;
    const double t0_3 = (s & 1) ? p.s7 : p.s6;
    const double t0_4 = (s & 1) ? p.s9 : p.s8;
    const double t0_5 = (s & 1) ? p.sb : p.sa;
    const double t0_6 = (s & 1) ? p.sd : p.sc;
    const double t0_7 = (s & 1) ? p.sf : p.se;
    const double t1_0 = (s & 2) ? t0_1 : t0_0;
    const double t1_1 = (s & 2) ? t0_3 : t0_2;
    const double t1_2 = (s & 2) ? t0_5 : t0_4;
    const double t1_3 = (s & 2) ? t0_7 : t0_6;
    const double a0 = (s & 4) ? t1_1 : t1_0;
    const double a1 = (s & 4) ? t1_3 : t1_2;
    return (s & 8) ? a1 : a0;
}

// Fused (value, index) min over 16 cand/lane x 64 lanes; ties -> smallest
// j = (k<<6)|l (np.argmin first-occurrence). ROUND-3 form (measured fastest):
// fmin TREE (depth 4, ILP) -> value-only f64 DPP min -> binary walk down the
// stored partials for the local smallest-k -> i32 key min-DPP for the global
// smallest-j.
__device__ __forceinline__ void lexpair(v16d c, int l,
                                        double& gv_o, int& jm_o) {
    const double a0 = fmin(c.s0, c.s1), a1 = fmin(c.s2, c.s3),
                 a2 = fmin(c.s4, c.s5), a3 = fmin(c.s6, c.s7),
                 a4 = fmin(c.s8, c.s9), a5 = fmin(c.sa, c.sb),
                 a6 = fmin(c.sc, c.sd), a7 = fmin(c.se, c.sf);
    const double b0 = fmin(a0, a1), b1 = fmin(a2, a3),
                 b2 = fmin(a4, a5), b3 = fmin(a6, a7);
    const double d0 = fmin(b0, b1), d1 = fmin(b2, b3);
    const double vloc = fmin(d0, d1);
    double v = vloc;
#define VS_(C) { const double pv = dpp_f64<C>(v); v = fmin(pv, v); }
    VS_(ROR1) VS_(ROR2) VS_(ROR4) VS_(ROR8) VS_(BC15) VS_(BC31)
#undef VS_
    const double gv = readlane_f64c(v, 63);
    const int bit3 = (d0 == gv) ? 0 : 1;
    const double bsel = bit3 ? b2 : b0;
    const int bit2 = (bsel == gv) ? 0 : 1;
    const double asel = bit2 ? (bit3 ? a6 : a2) : (bit3 ? a4 : a0);
    const int bit1 = (asel == gv) ? 0 : 1;
    const double csel = bit1 ? (bit2 ? (bit3 ? c.se : c.s6) : (bit3 ? c.sa : c.s2))
                             : (bit2 ? (bit3 ? c.sc : c.s4) : (bit3 ? c.s8 : c.s0));
    const int bit0 = (csel == gv) ? 0 : 1;
    const int kloc = (bit3 << 3) | (bit2 << 2) | (bit1 << 1) | bit0;
    int key = (vloc == gv) ? ((kloc << 6) | l) : 0x7FFFFFFF;
#define KS_(C) { const int pk = dpp_i32<C>(key); key = (pk < key) ? pk : key; }
    KS_(ROR1) KS_(ROR2) KS_(ROR4) KS_(ROR8) KS_(BC15) KS_(BC31)
#undef KS_
    jm_o = readlane_i32c(key, 63);
    gv_o = gv;
}

// ---- matcher core (round-3 verified logic, loader-templated) -------------
// LDS-free JV matcher on one wave. See earlier rounds for invariants/proofs.
// All per-lane state in ext_vectors with compile-time element access: NO
// alloca may exist (round-1 lesson: promote-alloca-to-LDS cost 40us).
// NEEDS ~96-120 VGPRs: never cap below that (round-7 lesson: a 64-VGPR cap
// spilled to scratch, WRITE_SIZE 256KB->11.7MB, matcher 68->160us).
template<class LR>
__device__ __forceinline__ void matcher_core(
    const int l, const int g, LR load_row,
    const float pre_v, const int pre_j, const float sec_v, const int sec_j,
    float* __restrict__ out_ind_b, float* __restrict__ out_mask_b)
{
    const double INF = __builtin_inf();
    double u_rep = 0.0;       // u[l]
    double m_rec = 0.0;       // minv at the pop that added row l to SR
    bool   inSR  = false;
    int    c4r_rep = -1;      // col4row[l]
    unsigned asg   = 0u;      // bit k: column l+64k assigned (output only)
    unsigned dirty = 0u;      // bit k: v of column l+64k STRICTLY changed
    v16d v_r, sh_r;
    v16i path;
    v16f c_cur, c_i;
#define INI_(K,H) { v_r.s##H = 0.0; sh_r.s##H = 0.0; path.s##H = 0; }
    REP16(INI_)
#undef INI_
#define Z16_(K,H) { c_cur.s##H = 0.0f; c_i.s##H = 0.0f; }
    REP16(Z16_)
#undef Z16_

    for (int cur = 0; cur < g; ++cur) {
        // ---- step-1 argmin ----
        const float pre_vc = readlane_f32u(pre_v, cur);
        int jm = readlane_i32(pre_j, cur);
        double minv = (double)pre_vc;
        bool have_cur = false;
        {
            const int ow1 = jm & 63, sl1 = jm >> 6;
            const unsigned d1 = (unsigned)readlane_i32((int)dirty, ow1);
            if ((d1 >> sl1) & 1u) {
                // best column dirty -> try exact second-best resolution
                const float sv_c = readlane_f32u(sec_v, cur);
                const int   sj_c = readlane_i32(sec_j, cur);
                const unsigned d2 = (unsigned)readlane_i32((int)dirty, sj_c & 63);
                if (!((d2 >> (sj_c >> 6)) & 1u) && (sj_c != jm)) {
                    const double vpj = readlane_f64(sel16v_d(v_r, sl1), ow1);
                    const double vA = (double)pre_vc - vpj;   // exact: (f64)cost - v
                    const double vB = (double)sv_c;           // clean: v == 0
                    const bool tt = (vB < vA) || ((vB == vA) && (sj_c < jm));
                    minv = tt ? vB : vA;
                    jm   = tt ? sj_c : jm;
                } else {
                    c_cur = load_row(cur); have_cur = true;
                    v16d rr0;
#define RR0_(K,H) rr0.s##H = (double)c_cur.s##H - v_r.s##H;
                    REP16(RR0_)
#undef RR0_
                    lexpair(rr0, l, minv, jm);
                }
            }
        }
        const unsigned long long mk0 = __ballot(c4r_rep == jm);

        if (mk0 == 0ull) {
            // ---- fast row: O(1) bookkeeping (u,v of others unchanged) ----
            u_rep   = (l == cur) ? u_rep + minv : u_rep;
            c4r_rep = (l == cur) ? jm           : c4r_rep;
            asg     = (l == (jm & 63)) ? (asg | (1u << (jm >> 6))) : asg;
        } else {
            // ---- slow path: exact reference Dijkstra from step-1 state ----
            if (!have_cur) c_cur = load_row(cur);
            int i = (int)__builtin_ctzll(mk0);
            c_i = load_row(i);
            double ui = readlane_f64(u_rep, i);
            unsigned sc = (l == (jm & 63)) ? (1u << (jm >> 6)) : 0u;
            inSR  = (l == i);
            m_rec = minv;                            // valid only where inSR
#define SH0_(K,H) { sh_r.s##H = (double)c_cur.s##H - v_r.s##H; path.s##H = cur; }
            REP16(SH0_)
#undef SH0_

            int sink = -1;
            while (sink < 0) {
                v16d cand;
#define DST_(K,H) { const double rr = ((minv + (double)c_i.s##H) - ui) - v_r.s##H; \
                    const bool notSC = !((sc >> K) & 1u); \
                    const bool upd = notSC && (rr < sh_r.s##H); /* strict < */ \
                    sh_r.s##H = upd ? rr : sh_r.s##H; \
                    path.s##H = upd ? i : path.s##H; \
                    cand.s##H = notSC ? sh_r.s##H : INF; }
                REP16(DST_)
#undef DST_
                lexpair(cand, l, minv, jm);
                const unsigned long long mk = __ballot(c4r_rep == jm);
                if (l == (jm & 63)) sc |= (1u << (jm >> 6));
                if (mk == 0ull) {
                    sink = jm;
                } else {
                    i = (int)__builtin_ctzll(mk);
                    c_i = load_row(i);
                    if (l == i) { inSR = true; m_rec = minv; }
                    ui = readlane_f64(u_rep, i);
                }
            }

            // dual updates (reference order: u, then v, then augment).
            if (l == cur)       u_rep += minv;
            else if (inSR)      u_rep += minv - m_rec;
            unsigned chg = 0u;
#define VUP_(K,H) { const bool in_sc = (sc >> K) & 1u; \
                    const double nv = v_r.s##H - (minv - sh_r.s##H); \
                    chg = (in_sc && (sh_r.s##H != minv)) ? (chg | (1u << K)) : chg; \
                    v_r.s##H = in_sc ? nv : v_r.s##H; }
            REP16(VUP_)
#undef VUP_
            dirty |= chg;   // EXACT: only strictly-changed columns

            // augment along alternating path
            int j = sink;
            while (true) {
                const int so = j & 63, ss = j >> 6;
                const int ii = readlane_i32(sel16v_i(path, ss), so);
                const int nj = readlane_i32(c4r_rep, ii);   // old col4row[ii]
                asg     = (l == so) ? (asg | (1u << ss)) : asg;
                c4r_rep = (l == ii) ? j : c4r_rep;
                j = nj;
                if (ii == cur) break;
            }
        }
    }

    // ---- output: mask/zeros from asg bits; indices via one scatter ----
#define OUT_(K,H) { const int jj = l + (K << 6); const bool a_ = (asg >> K) & 1u; \
    out_mask_b[jj] = a_ ? 1.0f : 0.0f; \
    if (!a_) out_ind_b[jj] = 0.0f; }
    REP16(OUT_)
#undef OUT_
    if (c4r_rep >= 0) out_ind_b[c4r_rep] = (float)l;  // disjoint from zeros
}

// ---- ONE launch, two roles (544 blocks x 256 threads) --------------------
// Blocks 32..543: build (512-way parallel, identical arithmetic/outputs to
// the two-kernel build). Blocks 0..31: matcher for batch b = blockIdx.x,
// gated on flags[b] reaching 16 (release-add by each of b's chunk blocks;
// acquire-spin by the matcher). This topology was VERIFIED correct in round
// 7 (absmax 0.0); its only defect was __launch_bounds__(256,4) -> 64-VGPR
// cap -> scratch spills (WRITE_SIZE 11.7MB, matcher 160us). Fix: (256,1) --
// the exact bound round-6's matcher_ws used to get 96 VGPR / 0 spills /
// 68us. NOT cooperative launch: hipLaunchCooperativeKernel breaks the
// harness's hipGraph capture (round-8 failure).
// Deadlock audit at (256,1): guaranteed >=1 block/CU -> >=256 slots; only
// 32 blocks spin; >=224 slots remain for the 512 build blocks, which always
// retire -> forward progress under any dispatch order. At ~96 VGPR the real
// occupancy is 4 blocks/CU (1024 slots) so all 544 are co-resident anyway.
__global__ __launch_bounds__(256, 1) void fused2_k(
    const float* __restrict__ obj, const float* __restrict__ cd,
    const float* __restrict__ gi, const int* __restrict__ ngt,
    float* __restrict__ ct,
    float* __restrict__ pv, int* __restrict__ pj,
    float* __restrict__ pv2, int* __restrict__ pj2,
    unsigned* __restrict__ flags,
    float* __restrict__ out_ind, float* __restrict__ out_mask)
{
    __shared__ float tile[64][65];
    const int t   = threadIdx.x;
    const int bid = blockIdx.x;

    if (bid >= B_) {
        // ================= build role =================
        const int n0 = bid - B_;
        const int b  = (n0 & 7) + (((n0 >> 3) & 3) << 3);   // batch (== bid mod 8)
        const int cb = n0 >> 5;                             // column chunk 0..15
        const int jb = cb << 6;
        const float* objb = obj + (b << 10);
        const float4* cd4 = (const float4*)(cd + ((size_t)b << 16));
        const float4* gi4 = (const float4*)(gi + ((size_t)b << 16));

        #pragma unroll
        for (int p = 0; p < 4; ++p) {
            const int f  = t + (p << 8);
            const int jj = f >> 4;          // 0..63
            const int q  = f & 15;
            const int i0 = q << 2;          // 0,4,..,60
            const int j  = jb + jj;
            const float om = __fmul_rn(5.0f, -objb[j]);
            const float4 c4 = cd4[(j << 4) + q];
            const float4 q4 = gi4[(j << 4) + q];
            tile[i0 + 0][jj] = __fadd_rn(__fadd_rn(om, __fmul_rn(10.0f, c4.x)), __fmul_rn(2.0f, -q4.x));
            tile[i0 + 1][jj] = __fadd_rn(__fadd_rn(om, __fmul_rn(10.0f, c4.y)), __fmul_rn(2.0f, -q4.y));
            tile[i0 + 2][jj] = __fadd_rn(__fadd_rn(om, __fmul_rn(10.0f, c4.z)), __fmul_rn(2.0f, -q4.z));
            tile[i0 + 3][jj] = __fadd_rn(__fadd_rn(om, __fmul_rn(10.0f, c4.w)), __fmul_rn(2.0f, -q4.w));
        }
        __syncthreads();
        #pragma unroll
        for (int r = 0; r < 16; ++r) {      // coalesced ct write
            const int idx = (r << 8) + t;
            const int i = idx >> 6, j2 = idx & 63;
            ct[(((size_t)(b << 6) + i) << 10) + jb + j2] = tile[i][j2];
        }
        if (t < 64) {                        // (best, second) for row t
            float bv = tile[t][0]; int bc = 0;
            float sv = 1e30f;      int sc2 = 0;
            #pragma unroll 8
            for (int c = 1; c < 64; ++c) {
                const float v = tile[t][c];
                const bool t1 = v < bv;                 // strict: first occurrence
                const bool t2 = (!t1) && (v < sv);
                sv  = t1 ? bv : (t2 ? v : sv);
                sc2 = t1 ? bc : (t2 ? c : sc2);
                bv  = t1 ? v : bv;
                bc  = t1 ? c : bc;
            }
            const int o = (((b << 6) + t) << 4) + cb;
            pv[o]  = bv;  pj[o]  = jb + bc;
            pv2[o] = sv;  pj2[o] = jb + sc2;
        }
        __syncthreads();   // all this block's stores drained (vmcnt0 at barrier)
        if (t == 0)        // publish: device-scope release add
            __hip_atomic_fetch_add(&flags[b], 1u, __ATOMIC_RELEASE,
                                   __HIP_MEMORY_SCOPE_AGENT);
        return;
    }

    // ================= matcher role =================
    const int b = bid;
    if (t == 0) {          // acquire-spin until this batch's 16 chunks done
        while (__hip_atomic_load(&flags[b], __ATOMIC_ACQUIRE,
                                 __HIP_MEMORY_SCOPE_AGENT) < 16u)
            __builtin_amdgcn_s_sleep(2);
    }
    __syncthreads();       // whole block ordered behind the acquire

    const float* ctb = ct + ((size_t)(b << 6) << 10);
    if (t >= 64) {
        // ---- L2-warm waves (round-6, +7.5us): pull the 256KB slice from
        // LLC into this XCD's L2; DCE-protected reads, then retire. ----
        const float4* c4p = (const float4*)ctb;     // 16384 float4 per batch
        for (int n = t - 64; n < 16384; n += 192) {
            const float4 x = c4p[n];
            asm volatile("" :: "v"(x.x), "v"(x.y), "v"(x.z), "v"(x.w));
        }
        return;
    }

    const int l = t;
    const int g = ngt[b];

    // ---- per-row precomputed (best, second) -> lane l = row l ----
    const int base = ((b << 6) + l) << 4;
    const float4* pvq = (const float4*)(pv  + base);
    const int4*   pjq = (const int4*)(pj  + base);
    const float4* svq = (const float4*)(pv2 + base);
    const int4*   sjq = (const int4*)(pj2 + base);
    const float4 pA = pvq[0], pB = pvq[1], pC = pvq[2], pD = pvq[3];
    const int4   jA = pjq[0], jB = pjq[1], jC = pjq[2], jD = pjq[3];
    const float4 sA = svq[0], sB = svq[1], sC = svq[2], sD = svq[3];
    const int4   tA = sjq[0], tB = sjq[1], tC = sjq[2], tD = sjq[3];
    float bv = pA.x; int bj = jA.x; float sv = sA.x; int sj = tA.x;
    // merge chunks ascending; (best, second) both first-occurrence exact
#define MERGE_(CV,CJ,C2V,C2J) { const bool nb = (CV) < bv; \
    const bool s1 = (C2V) < bv; const bool s2 = (CV) < sv; \
    const float nsv = nb ? (s1 ? (C2V) : bv) : (s2 ? (CV) : sv); \
    const int   nsj = nb ? (s1 ? (C2J) : bj) : (s2 ? (CJ) : sj); \
    bj = nb ? (CJ) : bj; bv = nb ? (CV) : bv; sv = nsv; sj = nsj; }
    MERGE_(pA.y,jA.y,sA.y,tA.y) MERGE_(pA.z,jA.z,sA.z,tA.z) MERGE_(pA.w,jA.w,sA.w,tA.w)
    MERGE_(pB.x,jB.x,sB.x,tB.x) MERGE_(pB.y,jB.y,sB.y,tB.y) MERGE_(pB.z,jB.z,sB.z,tB.z) MERGE_(pB.w,jB.w,sB.w,tB.w)
    MERGE_(pC.x,jC.x,sC.x,tC.x) MERGE_(pC.y,jC.y,sC.y,tC.y) MERGE_(pC.z,jC.z,sC.z,tC.z) MERGE_(pC.w,jC.w,sC.w,tC.w)
    MERGE_(pD.x,jD.x,sD.x,tD.x) MERGE_(pD.y,jD.y,sD.y,tD.y) MERGE_(pD.z,jD.z,sD.z,tD.z) MERGE_(pD.w,jD.w,sD.w,tD.w)
#undef MERGE_

    auto load_row = [&](int ri) -> v16f {
        v16f d; const float* rp_ = ctb + ((size_t)ri << 10) + l;
#define LDW_(D,K,H) D.s##H = rp_[(K) << 6];
        REP16A(LDW_, d)
#undef LDW_
        return d;
    };
    matcher_core(l, g, load_row, bv, bj, sv, sj,
                 out_ind + (b << 10), out_mask + (b << 10));
}

// ---- no-workspace fallback: compute rows on the fly ----------------------
__global__ __launch_bounds__(64, 1) void matcher_nws(
    const float* __restrict__ obj, const float* __restrict__ cd,
    const float* __restrict__ gi, const int* __restrict__ ngt,
    float* __restrict__ out_ind, float* __restrict__ out_mask)
{
    const int b = blockIdx.x;
    const int l = threadIdx.x;
    const int g = ngt[b];
    const float* objb = obj + (b << 10);
    const float* cdb  = cd + ((size_t)b << 16);
    const float* gib  = gi + ((size_t)b << 16);

    v16f objm;
#define OBJI_(K,H) objm.s##H = __fmul_rn(5.0f, -objb[l + (K << 6)]);
    REP16(OBJI_)
#undef OBJI_
    auto load_row = [&](int ri) -> v16f {
        v16f d;
#define LDN_(D,K,H) { const int idx_ = ((l + ((K) << 6)) << 6) + ri; \
    D.s##H = __fadd_rn(__fadd_rn(objm.s##H, __fmul_rn(10.0f, cdb[idx_])), \
                       __fmul_rn(2.0f, -gib[idx_])); }
        REP16A(LDN_, d)
#undef LDN_
        return d;
    };

    float pre_v = 0.0f; int pre_j = 0;
    for (int i = 0; i < g; ++i) {            // cooperative per-row argmin
        v16f c = load_row(i);
        v16d c64;
#define CV_(K,H) c64.s##H = (double)c.s##H;
        REP16(CV_)
#undef CV_
        double gv; int j0;
        lexpair(c64, l, gv, j0);
        pre_v = (l == i) ? (float)gv : pre_v;
        pre_j = (l == i) ? j0 : pre_j;
    }
    // sec == pre: dirty best -> sec also dirty (same col) -> full recompute
    matcher_core(l, g, load_row, pre_v, pre_j, pre_v, pre_j,
                 out_ind + (b << 10), out_mask + (b << 10));
}

extern "C" void kernel_launch(void* const* d_in, const int* in_sizes, int n_in,
                              void* d_out, int out_size, void* d_ws, size_t ws_size,
                              hipStream_t stream)
{
    const float* obj = (const float*)d_in[1];
    const float* cd  = (const float*)d_in[2];
    const float* gi  = (const float*)d_in[3];
    const int*   ngt = (const int*)d_in[4];
    float* out0 = (float*)d_out;
    float* out1 = out0 + B_ * Q_;

    const size_t ct_b = (size_t)B_ * G_ * Q_ * sizeof(float);       // 8 MB
    const size_t pv_b = (size_t)B_ * G_ * 16 * sizeof(float);       // 128 KB
    const size_t fl_b = B_ * sizeof(unsigned);                      // 128 B
    if (ws_size >= ct_b + 4 * pv_b + fl_b) {
        float*    ct    = (float*)d_ws;
        float*    pv    = (float*)((char*)d_ws + ct_b);
        int*      pj    = (int*)  ((char*)d_ws + ct_b + pv_b);
        float*    pv2   = (float*)((char*)d_ws + ct_b + 2 * pv_b);
        int*      pj2   = (int*)  ((char*)d_ws + ct_b + 3 * pv_b);
        unsigned* flags = (unsigned*)((char*)d_ws + ct_b + 4 * pv_b);
        hipMemsetAsync(flags, 0, fl_b, stream);
        fused2_k<<<B_ + 16 * B_, 256, 0, stream>>>(obj, cd, gi, ngt, ct,
                                                   pv, pj, pv2, pj2, flags,
                                                   out0, out1);
    } else {
        matcher_nws<<<B_, 64, 0, stream>>>(obj, cd, gi, ngt, out0, out1);
    }
}

// Round 10
// 156.976 us; speedup vs baseline: 1.5606x; 1.1159x over previous
//
#include <hip/hip_runtime.h>
#include <math.h>

#define B_ 32
#define Q_ 1024
#define G_ 64
#define K16 16   // columns per lane in matcher (Q_ / 64)

typedef double v16d __attribute__((ext_vector_type(16)));
typedef float  v16f __attribute__((ext_vector_type(16)));
typedef int    v16i __attribute__((ext_vector_type(16)));

// X-macro: OP(K, H) with K = int index, H = hex element suffix
#define REP16(OP) OP(0,0) OP(1,1) OP(2,2) OP(3,3) OP(4,4) OP(5,5) OP(6,6) OP(7,7) \
                  OP(8,8) OP(9,9) OP(10,a) OP(11,b) OP(12,c) OP(13,d) OP(14,e) OP(15,f)
#define REP16A(OP,A) OP(A,0,0) OP(A,1,1) OP(A,2,2) OP(A,3,3) OP(A,4,4) OP(A,5,5) OP(A,6,6) OP(A,7,7) \
                     OP(A,8,8) OP(A,9,9) OP(A,10,a) OP(A,11,b) OP(A,12,c) OP(A,13,d) OP(A,14,e) OP(A,15,f)

// ---- cross-lane helpers -------------------------------------------------
#define ROR1 0x121
#define ROR2 0x122
#define ROR4 0x124
#define ROR8 0x128
#define BC15 0x142
#define BC31 0x143

template<int CTRL>
__device__ __forceinline__ double dpp_f64(double x) {
    union { double d; int i[2]; } a; a.d = x;
    union { int i[2]; double d; } r;
    r.i[0] = __builtin_amdgcn_update_dpp(a.i[0], a.i[0], CTRL, 0xF, 0xF, false);
    r.i[1] = __builtin_amdgcn_update_dpp(a.i[1], a.i[1], CTRL, 0xF, 0xF, false);
    return r.d;
}
template<int CTRL>
__device__ __forceinline__ int dpp_i32(int x) {
    return __builtin_amdgcn_update_dpp(x, x, CTRL, 0xF, 0xF, false);
}

__device__ __forceinline__ double readlane_f64(double x, int sl) {
    const int s = __builtin_amdgcn_readfirstlane(sl);
    union { double d; int i2[2]; } a; a.d = x;
    union { int i2[2]; double d; } r;
    r.i2[0] = __builtin_amdgcn_readlane(a.i2[0], s);
    r.i2[1] = __builtin_amdgcn_readlane(a.i2[1], s);
    return r.d;
}
__device__ __forceinline__ double readlane_f64c(double x, int sl) {  // const lane
    union { double d; int i2[2]; } a; a.d = x;
    union { int i2[2]; double d; } r;
    r.i2[0] = __builtin_amdgcn_readlane(a.i2[0], sl);
    r.i2[1] = __builtin_amdgcn_readlane(a.i2[1], sl);
    return r.d;
}
__device__ __forceinline__ float readlane_f32u(float x, int sl) {
    union { float f; int i; } a; a.f = x;
    union { int i; float f; } r;
    r.i = __builtin_amdgcn_readlane(a.i, __builtin_amdgcn_readfirstlane(sl));
    return r.f;
}
__device__ __forceinline__ int readlane_i32(int x, int sl) {
    return __builtin_amdgcn_readlane(x, __builtin_amdgcn_readfirstlane(sl));
}
__device__ __forceinline__ int readlane_i32c(int x, int sl) {
    return __builtin_amdgcn_readlane(x, sl);
}

// tree-select element s (uniform, 0..15) of a v16i held in registers
__device__ __forceinline__ int sel16v_i(v16i p, int s) {
    const int t0_0 = (s & 1) ? p.s1 : p.s0;
    const int t0_1 = (s & 1) ? p.s3 : p.s2;
    const int t0_2 = (s & 1) ? p.s5 : p.s4;
    const int t0_3 = (s & 1) ? p.s7 : p.s6;
    const int t0_4 = (s & 1) ? p.s9 : p.s8;
    const int t0_5 = (s & 1) ? p.sb : p.sa;
    const int t0_6 = (s & 1) ? p.sd : p.sc;
    const int t0_7 = (s & 1) ? p.sf : p.se;
    const int t1_0 = (s & 2) ? t0_1 : t0_0;
    const int t1_1 = (s & 2) ? t0_3 : t0_2;
    const int t1_2 = (s & 2) ? t0_5 : t0_4;
    const int t1_3 = (s & 2) ? t0_7 : t0_6;
    const int a0 = (s & 4) ? t1_1 : t1_0;
    const int a1 = (s & 4) ? t1_3 : t1_2;
    return (s & 8) ? a1 : a0;
}
__device__ __forceinline__ double sel16v_d(v16d p, int s) {
    const double t0_0 = (s & 1) ? p.s1 : p.s0;
    const double t0_1 = (s & 1) ? p.s3 : p.s2;
    const double t0_2 = (s & 1) ? p.s5 : p.s4;
    const double t0_3 = (s & 1) ? p.s7 : p.s6;
    const double t0_4 = (s & 1) ? p.s9 : p.s8;
    const double t0_5 = (s & 1) ? p.sb : p.sa;
    const double t0_6 = (s & 1) ? p.sd : p.sc;
    const double t0_7 = (s & 1) ? p.sf : p.se;
    const double t1_0 = (s & 2) ? t0_1 : t0_0;
    const double t1_1 = (s & 2) ? t0_3 : t0_2;
    const double t1_2 = (s & 2) ? t0_5 : t0_4;
    const double t1_3 = (s & 2) ? t0_7 : t0_6;
    const double a0 = (s & 4) ? t1_1 : t1_0;
    const double a1 = (s & 4) ? t1_3 : t1_2;
    return (s & 8) ? a1 : a0;
}

// Fused (value, index) min over 16 cand/lane x 64 lanes; ties -> smallest
// j = (k<<6)|l (np.argmin first-occurrence). ROUND-3 form (measured fastest):
// fmin TREE (depth 4, ILP) -> value-only f64 DPP min -> binary walk down the
// stored partials for the local smallest-k -> i32 key min-DPP for the global
// smallest-j.
__device__ __forceinline__ void lexpair(v16d c, int l,
                                        double& gv_o, int& jm_o) {
    const double a0 = fmin(c.s0, c.s1), a1 = fmin(c.s2, c.s3),
                 a2 = fmin(c.s4, c.s5), a3 = fmin(c.s6, c.s7),
                 a4 = fmin(c.s8, c.s9), a5 = fmin(c.sa, c.sb),
                 a6 = fmin(c.sc, c.sd), a7 = fmin(c.se, c.sf);
    const double b0 = fmin(a0, a1), b1 = fmin(a2, a3),
                 b2 = fmin(a4, a5), b3 = fmin(a6, a7);
    const double d0 = fmin(b0, b1), d1 = fmin(b2, b3);
    const double vloc = fmin(d0, d1);
    double v = vloc;
#define VS_(C) { const double pv = dpp_f64<C>(v); v = fmin(pv, v); }
    VS_(ROR1) VS_(ROR2) VS_(ROR4) VS_(ROR8) VS_(BC15) VS_(BC31)
#undef VS_
    const double gv = readlane_f64c(v, 63);
    const int bit3 = (d0 == gv) ? 0 : 1;
    const double bsel = bit3 ? b2 : b0;
    const int bit2 = (bsel == gv) ? 0 : 1;
    const double asel = bit2 ? (bit3 ? a6 : a2) : (bit3 ? a4 : a0);
    const int bit1 = (asel == gv) ? 0 : 1;
    const double csel = bit1 ? (bit2 ? (bit3 ? c.se : c.s6) : (bit3 ? c.sa : c.s2))
                             : (bit2 ? (bit3 ? c.sc : c.s4) : (bit3 ? c.s8 : c.s0));
    const int bit0 = (csel == gv) ? 0 : 1;
    const int kloc = (bit3 << 3) | (bit2 << 2) | (bit1 << 1) | bit0;
    int key = (vloc == gv) ? ((kloc << 6) | l) : 0x7FFFFFFF;
#define KS_(C) { const int pk = dpp_i32<C>(key); key = (pk < key) ? pk : key; }
    KS_(ROR1) KS_(ROR2) KS_(ROR4) KS_(ROR8) KS_(BC15) KS_(BC31)
#undef KS_
    jm_o = readlane_i32c(key, 63);
    gv_o = gv;
}

// K1: 512 blocks (16 jb-chunks x 32 batches). Builds transposed ct[b][i][j]
// (exact reference f32 arithmetic) AND per-row (best, second-best) over its
// 64-col chunk (strict <, ascending scan => first occurrence for both).
// NOTE (rounds 4/7/9): do NOT fuse this into the matcher launch. Serializing
// build onto 32 blocks costs ~60us (R4); flag-gated single-launch fusion is
// correct but the in-kernel produce->consume path is ~25us slower than the
// kernel-boundary path (R7/R9: dirty-L2 reads + whole-grid build tail),
// and cooperative launch breaks the harness's hipGraph capture (R8).
__global__ __launch_bounds__(256) void build_kernel(
    const float* __restrict__ obj, const float* __restrict__ cd,
    const float* __restrict__ gi, float* __restrict__ ct,
    float* __restrict__ pv, int* __restrict__ pj,
    float* __restrict__ pv2, int* __restrict__ pj2)
{
    __shared__ float tile[64][65];
    const int b  = blockIdx.y;
    const int jb = blockIdx.x << 6;
    const int t  = threadIdx.x;
    const float* objb = obj + (b << 10);
    const float4* cd4 = (const float4*)(cd + ((size_t)b << 16));
    const float4* gi4 = (const float4*)(gi + ((size_t)b << 16));

    #pragma unroll
    for (int p = 0; p < 4; ++p) {
        const int f  = t + (p << 8);
        const int jj = f >> 4;          // 0..63
        const int q  = f & 15;
        const int i0 = q << 2;          // 0,4,..,60
        const int j  = jb + jj;
        const float om = __fmul_rn(5.0f, -objb[j]);
        const float4 c4 = cd4[(j << 4) + q];
        const float4 q4 = gi4[(j << 4) + q];
        tile[i0 + 0][jj] = __fadd_rn(__fadd_rn(om, __fmul_rn(10.0f, c4.x)), __fmul_rn(2.0f, -q4.x));
        tile[i0 + 1][jj] = __fadd_rn(__fadd_rn(om, __fmul_rn(10.0f, c4.y)), __fmul_rn(2.0f, -q4.y));
        tile[i0 + 2][jj] = __fadd_rn(__fadd_rn(om, __fmul_rn(10.0f, c4.z)), __fmul_rn(2.0f, -q4.z));
        tile[i0 + 3][jj] = __fadd_rn(__fadd_rn(om, __fmul_rn(10.0f, c4.w)), __fmul_rn(2.0f, -q4.w));
    }
    __syncthreads();
    #pragma unroll
    for (int r = 0; r < 16; ++r) {      // coalesced ct write
        const int idx = (r << 8) + t;
        const int i = idx >> 6, j2 = idx & 63;
        ct[(((size_t)(b << 6) + i) << 10) + jb + j2] = tile[i][j2];
    }
    if (t < 64) {                        // (best, second) for row t
        float bv = tile[t][0]; int bc = 0;
        float sv = 1e30f;      int sc2 = 0;
        #pragma unroll 8
        for (int c = 1; c < 64; ++c) {
            const float v = tile[t][c];
            const bool t1 = v < bv;                 // new best (strict: first occ)
            const bool t2 = (!t1) && (v < sv);      // new second
            sv  = t1 ? bv : (t2 ? v : sv);
            sc2 = t1 ? bc : (t2 ? c : sc2);
            bv  = t1 ? v : bv;
            bc  = t1 ? c : bc;
        }
        const int o = (((b << 6) + t) << 4) + blockIdx.x;
        pv[o]  = bv;  pj[o]  = jb + bc;
        pv2[o] = sv;  pj2[o] = jb + sc2;
    }
}

// ---- matcher core (round-3 verified logic, loader-templated) -------------
// LDS-free JV matcher on one wave.
//  - row4col derived on demand: i = ctz(ballot(c4r_rep == jm)); assigned <=> mask!=0
//  - step-1: precomputed (best, second) + EXACT dirty marking; full row reload
//    only when BOTH best and second columns are dirty.
//  - u-update for SR rows via m_rec (shortest frozen at pop == minv then).
// All per-lane state in ext_vectors with compile-time element access: NO
// alloca may exist (round-1 lesson: promote-alloca-to-LDS cost 40us).
// NEEDS ~96-120 VGPRs: never cap below that (round-7 lesson: a 64-VGPR cap
// spilled to scratch, WRITE_SIZE 256KB->11.7MB, matcher 68->160us).
template<class LR>
__device__ __forceinline__ void matcher_core(
    const int l, const int g, LR load_row,
    const float pre_v, const int pre_j, const float sec_v, const int sec_j,
    float* __restrict__ out_ind_b, float* __restrict__ out_mask_b)
{
    const double INF = __builtin_inf();
    double u_rep = 0.0;       // u[l]
    double m_rec = 0.0;       // minv at the pop that added row l to SR
    bool   inSR  = false;
    int    c4r_rep = -1;      // col4row[l]
    unsigned asg   = 0u;      // bit k: column l+64k assigned (output only)
    unsigned dirty = 0u;      // bit k: v of column l+64k STRICTLY changed
    v16d v_r, sh_r;
    v16i path;
    v16f c_cur, c_i;
#define INI_(K,H) { v_r.s##H = 0.0; sh_r.s##H = 0.0; path.s##H = 0; }
    REP16(INI_)
#undef INI_
#define Z16_(K,H) { c_cur.s##H = 0.0f; c_i.s##H = 0.0f; }
    REP16(Z16_)
#undef Z16_

    for (int cur = 0; cur < g; ++cur) {
        // ---- step-1 argmin ----
        const float pre_vc = readlane_f32u(pre_v, cur);
        int jm = readlane_i32(pre_j, cur);
        double minv = (double)pre_vc;
        bool have_cur = false;
        {
            const int ow1 = jm & 63, sl1 = jm >> 6;
            const unsigned d1 = (unsigned)readlane_i32((int)dirty, ow1);
            if ((d1 >> sl1) & 1u) {
                // best column dirty -> try exact second-best resolution
                const float sv_c = readlane_f32u(sec_v, cur);
                const int   sj_c = readlane_i32(sec_j, cur);
                const unsigned d2 = (unsigned)readlane_i32((int)dirty, sj_c & 63);
                if (!((d2 >> (sj_c >> 6)) & 1u) && (sj_c != jm)) {
                    const double vpj = readlane_f64(sel16v_d(v_r, sl1), ow1);
                    const double vA = (double)pre_vc - vpj;   // exact: (f64)cost - v
                    const double vB = (double)sv_c;           // clean: v == 0
                    const bool tt = (vB < vA) || ((vB == vA) && (sj_c < jm));
                    minv = tt ? vB : vA;
                    jm   = tt ? sj_c : jm;
                } else {
                    c_cur = load_row(cur); have_cur = true;
                    v16d rr0;
#define RR0_(K,H) rr0.s##H = (double)c_cur.s##H - v_r.s##H;
                    REP16(RR0_)
#undef RR0_
                    lexpair(rr0, l, minv, jm);
                }
            }
        }
        const unsigned long long mk0 = __ballot(c4r_rep == jm);

        if (mk0 == 0ull) {
            // ---- fast row: O(1) bookkeeping (u,v of others unchanged) ----
            u_rep   = (l == cur) ? u_rep + minv : u_rep;
            c4r_rep = (l == cur) ? jm           : c4r_rep;
            asg     = (l == (jm & 63)) ? (asg | (1u << (jm >> 6))) : asg;
        } else {
            // ---- slow path: exact reference Dijkstra from step-1 state ----
            if (!have_cur) c_cur = load_row(cur);
            int i = (int)__builtin_ctzll(mk0);
            c_i = load_row(i);
            double ui = readlane_f64(u_rep, i);
            unsigned sc = (l == (jm & 63)) ? (1u << (jm >> 6)) : 0u;
            inSR  = (l == i);
            m_rec = minv;                            // valid only where inSR
#define SH0_(K,H) { sh_r.s##H = (double)c_cur.s##H - v_r.s##H; path.s##H = cur; }
            REP16(SH0_)
#undef SH0_

            int sink = -1;
            while (sink < 0) {
                v16d cand;
#define DST_(K,H) { const double rr = ((minv + (double)c_i.s##H) - ui) - v_r.s##H; \
                    const bool notSC = !((sc >> K) & 1u); \
                    const bool upd = notSC && (rr < sh_r.s##H); /* strict < */ \
                    sh_r.s##H = upd ? rr : sh_r.s##H; \
                    path.s##H = upd ? i : path.s##H; \
                    cand.s##H = notSC ? sh_r.s##H : INF; }
                REP16(DST_)
#undef DST_
                lexpair(cand, l, minv, jm);
                const unsigned long long mk = __ballot(c4r_rep == jm);
                if (l == (jm & 63)) sc |= (1u << (jm >> 6));
                if (mk == 0ull) {
                    sink = jm;
                } else {
                    i = (int)__builtin_ctzll(mk);
                    c_i = load_row(i);
                    if (l == i) { inSR = true; m_rec = minv; }
                    ui = readlane_f64(u_rep, i);
                }
            }

            // dual updates (reference order: u, then v, then augment).
            if (l == cur)       u_rep += minv;
            else if (inSR)      u_rep += minv - m_rec;
            unsigned chg = 0u;
#define VUP_(K,H) { const bool in_sc = (sc >> K) & 1u; \
                    const double nv = v_r.s##H - (minv - sh_r.s##H); \
                    chg = (in_sc && (sh_r.s##H != minv)) ? (chg | (1u << K)) : chg; \
                    v_r.s##H = in_sc ? nv : v_r.s##H; }
            REP16(VUP_)
#undef VUP_
            dirty |= chg;   // EXACT: only strictly-changed columns

            // augment along alternating path
            int j = sink;
            while (true) {
                const int so = j & 63, ss = j >> 6;
                const int ii = readlane_i32(sel16v_i(path, ss), so);
                const int nj = readlane_i32(c4r_rep, ii);   // old col4row[ii]
                asg     = (l == so) ? (asg | (1u << ss)) : asg;
                c4r_rep = (l == ii) ? j : c4r_rep;
                j = nj;
                if (ii == cur) break;
            }
        }
    }

    // ---- output: mask/zeros from asg bits; indices via one scatter ----
#define OUT_(K,H) { const int jj = l + (K << 6); const bool a_ = (asg >> K) & 1u; \
    out_mask_b[jj] = a_ ? 1.0f : 0.0f; \
    if (!a_) out_ind_b[jj] = 0.0f; }
    REP16(OUT_)
#undef OUT_
    if (c4r_rep >= 0) out_ind_b[c4r_rep] = (float)l;  // disjoint from zeros
}

// K2 (workspace path): 32 blocks x 256 threads. Wave 0 runs the matcher;
// waves 1-3 stream the batch's FIRST g ROWS of the ct slice (linear from
// row 0 = matcher's cur order) to pull them from LLC into THIS XCD's L2,
// then retire (rows >= g are never read by the matcher -> skipping them
// halves the warm burst at mean g~32, relieving L2/LLC BW exactly when the
// matcher issues its first loads). L2 is cold at kernel start
// (kernel-boundary flush; round-5: FETCH identical under XCD-aligned
// grids), so without warming every first-touch row load pays LLC latency
// (~650cy) ON the serial chain. Warming was +7.5us in round 6.
__global__ __launch_bounds__(256, 1) void matcher_ws(
    const int* __restrict__ ngt, const float* __restrict__ ct,
    const float* __restrict__ pv, const int* __restrict__ pj,
    const float* __restrict__ pv2, const int* __restrict__ pj2,
    float* __restrict__ out_ind, float* __restrict__ out_mask)
{
    const int b = blockIdx.x;
    const int t = threadIdx.x;
    const int g = ngt[b];
    const float* ctb = ct + ((size_t)(b << 6) << 10);

    if (t >= 64) {
        // ---- L2-warm waves: read-only sweep of rows 0..g-1, DCE-protected ----
        const float4* c4p = (const float4*)ctb;     // 256 float4 per row
        const int nmax = g << 8;                    // g * 256 float4s
        for (int n = t - 64; n < nmax; n += 192) {
            const float4 x = c4p[n];
            asm volatile("" :: "v"(x.x), "v"(x.y), "v"(x.z), "v"(x.w));
        }
        return;
    }

    const int l = t;

    // ---- per-row precomputed (best, second) -> lane l = row l ----
    const int base = ((b << 6) + l) << 4;
    const float4* pvq = (const float4*)(pv  + base);
    const int4*   pjq = (const int4*)(pj  + base);
    const float4* svq = (const float4*)(pv2 + base);
    const int4*   sjq = (const int4*)(pj2 + base);
    const float4 pA = pvq[0], pB = pvq[1], pC = pvq[2], pD = pvq[3];
    const int4   jA = pjq[0], jB = pjq[1], jC = pjq[2], jD = pjq[3];
    const float4 sA = svq[0], sB = svq[1], sC = svq[2], sD = svq[3];
    const int4   tA = sjq[0], tB = sjq[1], tC = sjq[2], tD = sjq[3];
    float bv = pA.x; int bj = jA.x; float sv = sA.x; int sj = tA.x;
    // merge chunks ascending; (best, second) both first-occurrence exact
#define MERGE_(CV,CJ,C2V,C2J) { const bool nb = (CV) < bv; \
    const bool s1 = (C2V) < bv; const bool s2 = (CV) < sv; \
    const float nsv = nb ? (s1 ? (C2V) : bv) : (s2 ? (CV) : sv); \
    const int   nsj = nb ? (s1 ? (C2J) : bj) : (s2 ? (CJ) : sj); \
    bj = nb ? (CJ) : bj; bv = nb ? (CV) : bv; sv = nsv; sj = nsj; }
    MERGE_(pA.y,jA.y,sA.y,tA.y) MERGE_(pA.z,jA.z,sA.z,tA.z) MERGE_(pA.w,jA.w,sA.w,tA.w)
    MERGE_(pB.x,jB.x,sB.x,tB.x) MERGE_(pB.y,jB.y,sB.y,tB.y) MERGE_(pB.z,jB.z,sB.z,tB.z) MERGE_(pB.w,jB.w,sB.w,tB.w)
    MERGE_(pC.x,jC.x,sC.x,tC.x) MERGE_(pC.y,jC.y,sC.y,tC.y) MERGE_(pC.z,jC.z,sC.z,tC.z) MERGE_(pC.w,jC.w,sC.w,tC.w)
    MERGE_(pD.x,jD.x,sD.x,tD.x) MERGE_(pD.y,jD.y,sD.y,tD.y) MERGE_(pD.z,jD.z,sD.z,tD.z) MERGE_(pD.w,jD.w,sD.w,tD.w)
#undef MERGE_

    auto load_row = [&](int ri) -> v16f {
        v16f d; const float* rp_ = ctb + ((size_t)ri << 10) + l;
#define LDW_(D,K,H) D.s##H = rp_[(K) << 6];
        REP16A(LDW_, d)
#undef LDW_
        return d;
    };
    matcher_core(l, g, load_row, bv, bj, sv, sj,
                 out_ind + (b << 10), out_mask + (b << 10));
}

// ---- no-workspace fallback: compute rows on the fly ----------------------
__global__ __launch_bounds__(64, 1) void matcher_nws(
    const float* __restrict__ obj, const float* __restrict__ cd,
    const float* __restrict__ gi, const int* __restrict__ ngt,
    float* __restrict__ out_ind, float* __restrict__ out_mask)
{
    const int b = blockIdx.x;
    const int l = threadIdx.x;
    const int g = ngt[b];
    const float* objb = obj + (b << 10);
    const float* cdb  = cd + ((size_t)b << 16);
    const float* gib  = gi + ((size_t)b << 16);

    v16f objm;
#define OBJI_(K,H) objm.s##H = __fmul_rn(5.0f, -objb[l + (K << 6)]);
    REP16(OBJI_)
#undef OBJI_
    auto load_row = [&](int ri) -> v16f {
        v16f d;
#define LDN_(D,K,H) { const int idx_ = ((l + ((K) << 6)) << 6) + ri; \
    D.s##H = __fadd_rn(__fadd_rn(objm.s##H, __fmul_rn(10.0f, cdb[idx_])), \
                       __fmul_rn(2.0f, -gib[idx_])); }
        REP16A(LDN_, d)
#undef LDN_
        return d;
    };

    float pre_v = 0.0f; int pre_j = 0;
    for (int i = 0; i < g; ++i) {            // cooperative per-row argmin
        v16f c = load_row(i);
        v16d c64;
#define CV_(K,H) c64.s##H = (double)c.s##H;
        REP16(CV_)
#undef CV_
        double gv; int j0;
        lexpair(c64, l, gv, j0);
        pre_v = (l == i) ? (float)gv : pre_v;
        pre_j = (l == i) ? j0 : pre_j;
    }
    // sec == pre: dirty best -> sec also dirty (same col) -> full recompute
    matcher_core(l, g, load_row, pre_v, pre_j, pre_v, pre_j,
                 out_ind + (b << 10), out_mask + (b << 10));
}

extern "C" void kernel_launch(void* const* d_in, const int* in_sizes, int n_in,
                              void* d_out, int out_size, void* d_ws, size_t ws_size,
                              hipStream_t stream)
{
    const float* obj = (const float*)d_in[1];
    const float* cd  = (const float*)d_in[2];
    const float* gi  = (const float*)d_in[3];
    const int*   ngt = (const int*)d_in[4];
    float* out0 = (float*)d_out;
    float* out1 = out0 + B_ * Q_;

    const size_t ct_b = (size_t)B_ * G_ * Q_ * sizeof(float);       // 8 MB
    const size_t pv_b = (size_t)B_ * G_ * 16 * sizeof(float);       // 128 KB
    if (ws_size >= ct_b + 4 * pv_b) {
        float* ct  = (float*)d_ws;
        float* pv  = (float*)((char*)d_ws + ct_b);
        int*   pj  = (int*)  ((char*)d_ws + ct_b + pv_b);
        float* pv2 = (float*)((char*)d_ws + ct_b + 2 * pv_b);
        int*   pj2 = (int*)  ((char*)d_ws + ct_b + 3 * pv_b);
        build_kernel<<<dim3(16, B_), 256, 0, stream>>>(obj, cd, gi, ct, pv, pj, pv2, pj2);
        matcher_ws<<<B_, 256, 0, stream>>>(ngt, ct, pv, pj, pv2, pj2, out0, out1);
    } else {
        matcher_nws<<<B_, 64, 0, stream>>>(obj, cd, gi, ngt, out0, out1);
    }
}

// Round 11
// 155.673 us; speedup vs baseline: 1.5737x; 1.0084x over previous
//
#include <hip/hip_runtime.h>
#include <math.h>

#define B_ 32
#define Q_ 1024
#define G_ 64
#define K16 16   // columns per lane in matcher (Q_ / 64)

typedef double v16d __attribute__((ext_vector_type(16)));
typedef float  v16f __attribute__((ext_vector_type(16)));
typedef int    v16i __attribute__((ext_vector_type(16)));

// X-macro: OP(K, H) with K = int index, H = hex element suffix
#define REP16(OP) OP(0,0) OP(1,1) OP(2,2) OP(3,3) OP(4,4) OP(5,5) OP(6,6) OP(7,7) \
                  OP(8,8) OP(9,9) OP(10,a) OP(11,b) OP(12,c) OP(13,d) OP(14,e) OP(15,f)
#define REP16A(OP,A) OP(A,0,0) OP(A,1,1) OP(A,2,2) OP(A,3,3) OP(A,4,4) OP(A,5,5) OP(A,6,6) OP(A,7,7) \
                     OP(A,8,8) OP(A,9,9) OP(A,10,a) OP(A,11,b) OP(A,12,c) OP(A,13,d) OP(A,14,e) OP(A,15,f)

// ---- cross-lane helpers -------------------------------------------------
#define ROR1 0x121
#define ROR2 0x122
#define ROR4 0x124
#define ROR8 0x128
#define BC15 0x142
#define BC31 0x143

template<int CTRL>
__device__ __forceinline__ double dpp_f64(double x) {
    union { double d; int i[2]; } a; a.d = x;
    union { int i[2]; double d; } r;
    r.i[0] = __builtin_amdgcn_update_dpp(a.i[0], a.i[0], CTRL, 0xF, 0xF, false);
    r.i[1] = __builtin_amdgcn_update_dpp(a.i[1], a.i[1], CTRL, 0xF, 0xF, false);
    return r.d;
}
template<int CTRL>
__device__ __forceinline__ int dpp_i32(int x) {
    return __builtin_amdgcn_update_dpp(x, x, CTRL, 0xF, 0xF, false);
}

__device__ __forceinline__ double readlane_f64(double x, int sl) {
    const int s = __builtin_amdgcn_readfirstlane(sl);
    union { double d; int i2[2]; } a; a.d = x;
    union { int i2[2]; double d; } r;
    r.i2[0] = __builtin_amdgcn_readlane(a.i2[0], s);
    r.i2[1] = __builtin_amdgcn_readlane(a.i2[1], s);
    return r.d;
}
__device__ __forceinline__ double readlane_f64c(double x, int sl) {  // const lane
    union { double d; int i2[2]; } a; a.d = x;
    union { int i2[2]; double d; } r;
    r.i2[0] = __builtin_amdgcn_readlane(a.i2[0], sl);
    r.i2[1] = __builtin_amdgcn_readlane(a.i2[1], sl);
    return r.d;
}
__device__ __forceinline__ float readlane_f32u(float x, int sl) {
    union { float f; int i; } a; a.f = x;
    union { int i; float f; } r;
    r.i = __builtin_amdgcn_readlane(a.i, __builtin_amdgcn_readfirstlane(sl));
    return r.f;
}
__device__ __forceinline__ int readlane_i32(int x, int sl) {
    return __builtin_amdgcn_readlane(x, __builtin_amdgcn_readfirstlane(sl));
}
__device__ __forceinline__ int readlane_i32c(int x, int sl) {
    return __builtin_amdgcn_readlane(x, sl);
}

// tree-select element s (uniform, 0..15) of a v16i held in registers
__device__ __forceinline__ int sel16v_i(v16i p, int s) {
    const int t0_0 = (s & 1) ? p.s1 : p.s0;
    const int t0_1 = (s & 1) ? p.s3 : p.s2;
    const int t0_2 = (s & 1) ? p.s5 : p.s4;
    const int t0_3 = (s & 1) ? p.s7 : p.s6;
    const int t0_4 = (s & 1) ? p.s9 : p.s8;
    const int t0_5 = (s & 1) ? p.sb : p.sa;
    const int t0_6 = (s & 1) ? p.sd : p.sc;
    const int t0_7 = (s & 1) ? p.sf : p.se;
    const int t1_0 = (s & 2) ? t0_1 : t0_0;
    const int t1_1 = (s & 2) ? t0_3 : t0_2;
    const int t1_2 = (s & 2) ? t0_5 : t0_4;
    const int t1_3 = (s & 2) ? t0_7 : t0_6;
    const int a0 = (s & 4) ? t1_1 : t1_0;
    const int a1 = (s & 4) ? t1_3 : t1_2;
    return (s & 8) ? a1 : a0;
}
__device__ __forceinline__ double sel16v_d(v16d p, int s) {
    const double t0_0 = (s & 1) ? p.s1 : p.s0;
    const double t0_1 = (s & 1) ? p.s3 : p.s2;
    const double t0_2 = (s & 1) ? p.s5 : p.s4;
    const double t0_3 = (s & 1) ? p.s7 : p.s6;
    const double t0_4 = (s & 1) ? p.s9 : p.s8;
    const double t0_5 = (s & 1) ? p.sb : p.sa;
    const double t0_6 = (s & 1) ? p.sd : p.sc;
    const double t0_7 = (s & 1) ? p.sf : p.se;
    const double t1_0 = (s & 2) ? t0_1 : t0_0;
    const double t1_1 = (s & 2) ? t0_3 : t0_2;
    const double t1_2 = (s & 2) ? t0_5 : t0_4;
    const double t1_3 = (s & 2) ? t0_7 : t0_6;
    const double a0 = (s & 4) ? t1_1 : t1_0;
    const double a1 = (s & 4) ? t1_3 : t1_2;
    return (s & 8) ? a1 : a0;
}

// Fused (value, index) min over 16 cand/lane x 64 lanes; ties -> smallest
// j = (k<<6)|l (np.argmin first-occurrence). ROUND-3 form (measured fastest):
// fmin TREE (depth 4, ILP) -> value-only f64 DPP min -> binary walk down the
// stored partials for the local smallest-k -> i32 key min-DPP for the global
// smallest-j. (R5's fused (v,key) combine was 6% slower; speculative f32
// pre-argmin rejected by issue-arithmetic: wave issues in-order ~2cy/instr,
// pop has only ~220cy issue slack, spec network costs >120cy issue.)
__device__ __forceinline__ void lexpair(v16d c, int l,
                                        double& gv_o, int& jm_o) {
    const double a0 = fmin(c.s0, c.s1), a1 = fmin(c.s2, c.s3),
                 a2 = fmin(c.s4, c.s5), a3 = fmin(c.s6, c.s7),
                 a4 = fmin(c.s8, c.s9), a5 = fmin(c.sa, c.sb),
                 a6 = fmin(c.sc, c.sd), a7 = fmin(c.se, c.sf);
    const double b0 = fmin(a0, a1), b1 = fmin(a2, a3),
                 b2 = fmin(a4, a5), b3 = fmin(a6, a7);
    const double d0 = fmin(b0, b1), d1 = fmin(b2, b3);
    const double vloc = fmin(d0, d1);
    double v = vloc;
#define VS_(C) { const double pv = dpp_f64<C>(v); v = fmin(pv, v); }
    VS_(ROR1) VS_(ROR2) VS_(ROR4) VS_(ROR8) VS_(BC15) VS_(BC31)
#undef VS_
    const double gv = readlane_f64c(v, 63);
    const int bit3 = (d0 == gv) ? 0 : 1;
    const double bsel = bit3 ? b2 : b0;
    const int bit2 = (bsel == gv) ? 0 : 1;
    const double asel = bit2 ? (bit3 ? a6 : a2) : (bit3 ? a4 : a0);
    const int bit1 = (asel == gv) ? 0 : 1;
    const double csel = bit1 ? (bit2 ? (bit3 ? c.se : c.s6) : (bit3 ? c.sa : c.s2))
                             : (bit2 ? (bit3 ? c.sc : c.s4) : (bit3 ? c.s8 : c.s0));
    const int bit0 = (csel == gv) ? 0 : 1;
    const int kloc = (bit3 << 3) | (bit2 << 2) | (bit1 << 1) | bit0;
    int key = (vloc == gv) ? ((kloc << 6) | l) : 0x7FFFFFFF;
#define KS_(C) { const int pk = dpp_i32<C>(key); key = (pk < key) ? pk : key; }
    KS_(ROR1) KS_(ROR2) KS_(ROR4) KS_(ROR8) KS_(BC15) KS_(BC31)
#undef KS_
    jm_o = readlane_i32c(key, 63);
    gv_o = gv;
}

// K1: 512 blocks (16 jb-chunks x 32 batches). Builds transposed ct[b][i][j]
// (exact reference f32 arithmetic) AND per-row (best, second-best) over its
// 64-col chunk (strict <, ascending scan => first occurrence for both).
// NOTE (rounds 4/7/9): do NOT fuse this into the matcher launch. Serializing
// build onto 32 blocks costs ~60us (R4); flag-gated single-launch fusion is
// correct but the in-kernel produce->consume path is ~25us slower than the
// kernel-boundary path (R7/R9: dirty-L2 reads + whole-grid build tail),
// and cooperative launch breaks the harness's hipGraph capture (R8).
__global__ __launch_bounds__(256) void build_kernel(
    const float* __restrict__ obj, const float* __restrict__ cd,
    const float* __restrict__ gi, float* __restrict__ ct,
    float* __restrict__ pv, int* __restrict__ pj,
    float* __restrict__ pv2, int* __restrict__ pj2)
{
    __shared__ float tile[64][65];
    const int b  = blockIdx.y;
    const int jb = blockIdx.x << 6;
    const int t  = threadIdx.x;
    const float* objb = obj + (b << 10);
    const float4* cd4 = (const float4*)(cd + ((size_t)b << 16));
    const float4* gi4 = (const float4*)(gi + ((size_t)b << 16));

    #pragma unroll
    for (int p = 0; p < 4; ++p) {
        const int f  = t + (p << 8);
        const int jj = f >> 4;          // 0..63
        const int q  = f & 15;
        const int i0 = q << 2;          // 0,4,..,60
        const int j  = jb + jj;
        const float om = __fmul_rn(5.0f, -objb[j]);
        const float4 c4 = cd4[(j << 4) + q];
        const float4 q4 = gi4[(j << 4) + q];
        tile[i0 + 0][jj] = __fadd_rn(__fadd_rn(om, __fmul_rn(10.0f, c4.x)), __fmul_rn(2.0f, -q4.x));
        tile[i0 + 1][jj] = __fadd_rn(__fadd_rn(om, __fmul_rn(10.0f, c4.y)), __fmul_rn(2.0f, -q4.y));
        tile[i0 + 2][jj] = __fadd_rn(__fadd_rn(om, __fmul_rn(10.0f, c4.z)), __fmul_rn(2.0f, -q4.z));
        tile[i0 + 3][jj] = __fadd_rn(__fadd_rn(om, __fmul_rn(10.0f, c4.w)), __fmul_rn(2.0f, -q4.w));
    }
    __syncthreads();
    #pragma unroll
    for (int r = 0; r < 16; ++r) {      // coalesced ct write
        const int idx = (r << 8) + t;
        const int i = idx >> 6, j2 = idx & 63;
        ct[(((size_t)(b << 6) + i) << 10) + jb + j2] = tile[i][j2];
    }
    if (t < 64) {                        // (best, second) for row t
        float bv = tile[t][0]; int bc = 0;
        float sv = 1e30f;      int sc2 = 0;
        #pragma unroll 8
        for (int c = 1; c < 64; ++c) {
            const float v = tile[t][c];
            const bool t1 = v < bv;                 // new best (strict: first occ)
            const bool t2 = (!t1) && (v < sv);      // new second
            sv  = t1 ? bv : (t2 ? v : sv);
            sc2 = t1 ? bc : (t2 ? c : sc2);
            bv  = t1 ? v : bv;
            bc  = t1 ? c : bc;
        }
        const int o = (((b << 6) + t) << 4) + blockIdx.x;
        pv[o]  = bv;  pj[o]  = jb + bc;
        pv2[o] = sv;  pj2[o] = jb + sc2;
    }
}

// ---- matcher core (round-3 verified logic, loader-templated) -------------
// LDS-free JV matcher on one wave.
//  - row4col derived on demand: i = ctz(ballot(c4r_rep == jm)); assigned <=> mask!=0
//  - step-1: precomputed (best, second) + EXACT dirty marking; full row reload
//    only when BOTH best and second columns are dirty.
//  - u-update for SR rows via m_rec (shortest frozen at pop == minv then).
//  - R11: c_cur prefetched unconditionally at loop top -- the 16 loads issue
//    (~32cy) before step-1's ~200cy of readlane/ballot work, so the L2
//    round-trip is off the chain when the slow/dirty paths consume it. Fast
//    rows never read c_cur (compiler sinks the vmcnt wait into the branches).
// All per-lane state in ext_vectors with compile-time element access: NO
// alloca may exist (round-1 lesson: promote-alloca-to-LDS cost 40us).
// NEEDS ~96-120 VGPRs: never cap below that (round-7 lesson: a 64-VGPR cap
// spilled to scratch, WRITE_SIZE 256KB->11.7MB, matcher 68->160us).
template<class LR>
__device__ __forceinline__ void matcher_core(
    const int l, const int g, LR load_row,
    const float pre_v, const int pre_j, const float sec_v, const int sec_j,
    float* __restrict__ out_ind_b, float* __restrict__ out_mask_b)
{
    const double INF = __builtin_inf();
    double u_rep = 0.0;       // u[l]
    double m_rec = 0.0;       // minv at the pop that added row l to SR
    bool   inSR  = false;
    int    c4r_rep = -1;      // col4row[l]
    unsigned asg   = 0u;      // bit k: column l+64k assigned (output only)
    unsigned dirty = 0u;      // bit k: v of column l+64k STRICTLY changed
    v16d v_r, sh_r;
    v16i path;
    v16f c_cur, c_i;
#define INI_(K,H) { v_r.s##H = 0.0; sh_r.s##H = 0.0; path.s##H = 0; }
    REP16(INI_)
#undef INI_
#define Z16_(K,H) { c_cur.s##H = 0.0f; c_i.s##H = 0.0f; }
    REP16(Z16_)
#undef Z16_

    for (int cur = 0; cur < g; ++cur) {
        // ---- prefetch row cur (always in flight; consumed only on the
        // dirty-dirty recompute or the slow path) ----
        c_cur = load_row(cur);
        // ---- step-1 argmin ----
        const float pre_vc = readlane_f32u(pre_v, cur);
        int jm = readlane_i32(pre_j, cur);
        double minv = (double)pre_vc;
        {
            const int ow1 = jm & 63, sl1 = jm >> 6;
            const unsigned d1 = (unsigned)readlane_i32((int)dirty, ow1);
            if ((d1 >> sl1) & 1u) {
                // best column dirty -> try exact second-best resolution
                const float sv_c = readlane_f32u(sec_v, cur);
                const int   sj_c = readlane_i32(sec_j, cur);
                const unsigned d2 = (unsigned)readlane_i32((int)dirty, sj_c & 63);
                if (!((d2 >> (sj_c >> 6)) & 1u) && (sj_c != jm)) {
                    const double vpj = readlane_f64(sel16v_d(v_r, sl1), ow1);
                    const double vA = (double)pre_vc - vpj;   // exact: (f64)cost - v
                    const double vB = (double)sv_c;           // clean: v == 0
                    const bool tt = (vB < vA) || ((vB == vA) && (sj_c < jm));
                    minv = tt ? vB : vA;
                    jm   = tt ? sj_c : jm;
                } else {
                    v16d rr0;
#define RR0_(K,H) rr0.s##H = (double)c_cur.s##H - v_r.s##H;
                    REP16(RR0_)
#undef RR0_
                    lexpair(rr0, l, minv, jm);
                }
            }
        }
        const unsigned long long mk0 = __ballot(c4r_rep == jm);

        if (mk0 == 0ull) {
            // ---- fast row: O(1) bookkeeping (u,v of others unchanged) ----
            u_rep   = (l == cur) ? u_rep + minv : u_rep;
            c4r_rep = (l == cur) ? jm           : c4r_rep;
            asg     = (l == (jm & 63)) ? (asg | (1u << (jm >> 6))) : asg;
        } else {
            // ---- slow path: exact reference Dijkstra from step-1 state ----
            int i = (int)__builtin_ctzll(mk0);
            c_i = load_row(i);
            double ui = readlane_f64(u_rep, i);
            unsigned sc = (l == (jm & 63)) ? (1u << (jm >> 6)) : 0u;
            inSR  = (l == i);
            m_rec = minv;                            // valid only where inSR
#define SH0_(K,H) { sh_r.s##H = (double)c_cur.s##H - v_r.s##H; path.s##H = cur; }
            REP16(SH0_)
#undef SH0_

            int sink = -1;
            while (sink < 0) {
                v16d cand;
#define DST_(K,H) { const double rr = ((minv + (double)c_i.s##H) - ui) - v_r.s##H; \
                    const bool notSC = !((sc >> K) & 1u); \
                    const bool upd = notSC && (rr < sh_r.s##H); /* strict < */ \
                    sh_r.s##H = upd ? rr : sh_r.s##H; \
                    path.s##H = upd ? i : path.s##H; \
                    cand.s##H = notSC ? sh_r.s##H : INF; }
                REP16(DST_)
#undef DST_
                lexpair(cand, l, minv, jm);
                const unsigned long long mk = __ballot(c4r_rep == jm);
                if (l == (jm & 63)) sc |= (1u << (jm >> 6));
                if (mk == 0ull) {
                    sink = jm;
                } else {
                    i = (int)__builtin_ctzll(mk);
                    c_i = load_row(i);
                    if (l == i) { inSR = true; m_rec = minv; }
                    ui = readlane_f64(u_rep, i);
                }
            }

            // dual updates (reference order: u, then v, then augment).
            if (l == cur)       u_rep += minv;
            else if (inSR)      u_rep += minv - m_rec;
            unsigned chg = 0u;
#define VUP_(K,H) { const bool in_sc = (sc >> K) & 1u; \
                    const double nv = v_r.s##H - (minv - sh_r.s##H); \
                    chg = (in_sc && (sh_r.s##H != minv)) ? (chg | (1u << K)) : chg; \
                    v_r.s##H = in_sc ? nv : v_r.s##H; }
            REP16(VUP_)
#undef VUP_
            dirty |= chg;   // EXACT: only strictly-changed columns

            // augment along alternating path
            int j = sink;
            while (true) {
                const int so = j & 63, ss = j >> 6;
                const int ii = readlane_i32(sel16v_i(path, ss), so);
                const int nj = readlane_i32(c4r_rep, ii);   // old col4row[ii]
                asg     = (l == so) ? (asg | (1u << ss)) : asg;
                c4r_rep = (l == ii) ? j : c4r_rep;
                j = nj;
                if (ii == cur) break;
            }
        }
    }

    // ---- output: mask/zeros from asg bits; indices via one scatter ----
#define OUT_(K,H) { const int jj = l + (K << 6); const bool a_ = (asg >> K) & 1u; \
    out_mask_b[jj] = a_ ? 1.0f : 0.0f; \
    if (!a_) out_ind_b[jj] = 0.0f; }
    REP16(OUT_)
#undef OUT_
    if (c4r_rep >= 0) out_ind_b[c4r_rep] = (float)l;  // disjoint from zeros
}

// K2 (workspace path): 32 blocks x 256 threads. Wave 0 runs the matcher;
// waves 1-3 stream the batch's FIRST g ROWS of the ct slice (linear from
// row 0 = matcher's cur order) to pull them from LLC into THIS XCD's L2,
// then retire. L2 is cold at kernel start (kernel-boundary flush; round-5:
// FETCH identical under XCD-aligned grids); warming was +7.5us in round 6.
__global__ __launch_bounds__(256, 1) void matcher_ws(
    const int* __restrict__ ngt, const float* __restrict__ ct,
    const float* __restrict__ pv, const int* __restrict__ pj,
    const float* __restrict__ pv2, const int* __restrict__ pj2,
    float* __restrict__ out_ind, float* __restrict__ out_mask)
{
    const int b = blockIdx.x;
    const int t = threadIdx.x;
    const int g = ngt[b];
    const float* ctb = ct + ((size_t)(b << 6) << 10);

    if (t >= 64) {
        // ---- L2-warm waves: read-only sweep of rows 0..g-1, DCE-protected ----
        const float4* c4p = (const float4*)ctb;     // 256 float4 per row
        const int nmax = g << 8;                    // g * 256 float4s
        for (int n = t - 64; n < nmax; n += 192) {
            const float4 x = c4p[n];
            asm volatile("" :: "v"(x.x), "v"(x.y), "v"(x.z), "v"(x.w));
        }
        return;
    }

    const int l = t;

    // ---- per-row precomputed (best, second) -> lane l = row l ----
    const int base = ((b << 6) + l) << 4;
    const float4* pvq = (const float4*)(pv  + base);
    const int4*   pjq = (const int4*)(pj  + base);
    const float4* svq = (const float4*)(pv2 + base);
    const int4*   sjq = (const int4*)(pj2 + base);
    const float4 pA = pvq[0], pB = pvq[1], pC = pvq[2], pD = pvq[3];
    const int4   jA = pjq[0], jB = pjq[1], jC = pjq[2], jD = pjq[3];
    const float4 sA = svq[0], sB = svq[1], sC = svq[2], sD = svq[3];
    const int4   tA = sjq[0], tB = sjq[1], tC = sjq[2], tD = sjq[3];
    float bv = pA.x; int bj = jA.x; float sv = sA.x; int sj = tA.x;
    // merge chunks ascending; (best, second) both first-occurrence exact
#define MERGE_(CV,CJ,C2V,C2J) { const bool nb = (CV) < bv; \
    const bool s1 = (C2V) < bv; const bool s2 = (CV) < sv; \
    const float nsv = nb ? (s1 ? (C2V) : bv) : (s2 ? (CV) : sv); \
    const int   nsj = nb ? (s1 ? (C2J) : bj) : (s2 ? (CJ) : sj); \
    bj = nb ? (CJ) : bj; bv = nb ? (CV) : bv; sv = nsv; sj = nsj; }
    MERGE_(pA.y,jA.y,sA.y,tA.y) MERGE_(pA.z,jA.z,sA.z,tA.z) MERGE_(pA.w,jA.w,sA.w,tA.w)
    MERGE_(pB.x,jB.x,sB.x,tB.x) MERGE_(pB.y,jB.y,sB.y,tB.y) MERGE_(pB.z,jB.z,sB.z,tB.z) MERGE_(pB.w,jB.w,sB.w,tB.w)
    MERGE_(pC.x,jC.x,sC.x,tC.x) MERGE_(pC.y,jC.y,sC.y,tC.y) MERGE_(pC.z,jC.z,sC.z,tC.z) MERGE_(pC.w,jC.w,sC.w,tC.w)
    MERGE_(pD.x,jD.x,sD.x,tD.x) MERGE_(pD.y,jD.y,sD.y,tD.y) MERGE_(pD.z,jD.z,sD.z,tD.z) MERGE_(pD.w,jD.w,sD.w,tD.w)
#undef MERGE_

    auto load_row = [&](int ri) -> v16f {
        v16f d; const float* rp_ = ctb + ((size_t)ri << 10) + l;
#define LDW_(D,K,H) D.s##H = rp_[(K) << 6];
        REP16A(LDW_, d)
#undef LDW_
        return d;
    };
    matcher_core(l, g, load_row, bv, bj, sv, sj,
                 out_ind + (b << 10), out_mask + (b << 10));
}

// ---- no-workspace fallback: compute rows on the fly ----------------------
__global__ __launch_bounds__(64, 1) void matcher_nws(
    const float* __restrict__ obj, const float* __restrict__ cd,
    const float* __restrict__ gi, const int* __restrict__ ngt,
    float* __restrict__ out_ind, float* __restrict__ out_mask)
{
    const int b = blockIdx.x;
    const int l = threadIdx.x;
    const int g = ngt[b];
    const float* objb = obj + (b << 10);
    const float* cdb  = cd + ((size_t)b << 16);
    const float* gib  = gi + ((size_t)b << 16);

    v16f objm;
#define OBJI_(K,H) objm.s##H = __fmul_rn(5.0f, -objb[l + (K << 6)]);
    REP16(OBJI_)
#undef OBJI_
    auto load_row = [&](int ri) -> v16f {
        v16f d;
#define LDN_(D,K,H) { const int idx_ = ((l + ((K) << 6)) << 6) + ri; \
    D.s##H = __fadd_rn(__fadd_rn(objm.s##H, __fmul_rn(10.0f, cdb[idx_])), \
                       __fmul_rn(2.0f, -gib[idx_])); }
        REP16A(LDN_, d)
#undef LDN_
        return d;
    };

    float pre_v = 0.0f; int pre_j = 0;
    for (int i = 0; i < g; ++i) {            // cooperative per-row argmin
        v16f c = load_row(i);
        v16d c64;
#define CV_(K,H) c64.s##H = (double)c.s##H;
        REP16(CV_)
#undef CV_
        double gv; int j0;
        lexpair(c64, l, gv, j0);
        pre_v = (l == i) ? (float)gv : pre_v;
        pre_j = (l == i) ? j0 : pre_j;
    }
    // sec == pre: dirty best -> sec also dirty (same col) -> full recompute
    matcher_core(l, g, load_row, pre_v, pre_j, pre_v, pre_j,
                 out_ind + (b << 10), out_mask + (b << 10));
}

extern "C" void kernel_launch(void* const* d_in, const int* in_sizes, int n_in,
                              void* d_out, int out_size, void* d_ws, size_t ws_size,
                              hipStream_t stream)
{
    const float* obj = (const float*)d_in[1];
    const float* cd  = (const float*)d_in[2];
    const float* gi  = (const float*)d_in[3];
    const int*   ngt = (const int*)d_in[4];
    float* out0 = (float*)d_out;
    float* out1 = out0 + B_ * Q_;

    const size_t ct_b = (size_t)B_ * G_ * Q_ * sizeof(float);       // 8 MB
    const size_t pv_b = (size_t)B_ * G_ * 16 * sizeof(float);       // 128 KB
    if (ws_size >= ct_b + 4 * pv_b) {
        float* ct  = (float*)d_ws;
        float* pv  = (float*)((char*)d_ws + ct_b);
        int*   pj  = (int*)  ((char*)d_ws + ct_b + pv_b);
        float* pv2 = (float*)((char*)d_ws + ct_b + 2 * pv_b);
        int*   pj2 = (int*)  ((char*)d_ws + ct_b + 3 * pv_b);
        build_kernel<<<dim3(16, B_), 256, 0, stream>>>(obj, cd, gi, ct, pv, pj, pv2, pj2);
        matcher_ws<<<B_, 256, 0, stream>>>(ngt, ct, pv, pj, pv2, pj2, out0, out1);
    } else {
        matcher_nws<<<B_, 64, 0, stream>>>(obj, cd, gi, ngt, out0, out1);
    }
}

// Round 12
// 152.634 us; speedup vs baseline: 1.6050x; 1.0199x over previous
//
#include <hip/hip_runtime.h>
#include <math.h>

#define B_ 32
#define Q_ 1024
#define G_ 64
#define K16 16   // columns per lane in matcher (Q_ / 64)

typedef double v16d __attribute__((ext_vector_type(16)));
typedef float  v16f __attribute__((ext_vector_type(16)));
typedef int    v16i __attribute__((ext_vector_type(16)));

// X-macro: OP(K, H) with K = int index, H = hex element suffix
#define REP16(OP) OP(0,0) OP(1,1) OP(2,2) OP(3,3) OP(4,4) OP(5,5) OP(6,6) OP(7,7) \
                  OP(8,8) OP(9,9) OP(10,a) OP(11,b) OP(12,c) OP(13,d) OP(14,e) OP(15,f)
#define REP16A(OP,A) OP(A,0,0) OP(A,1,1) OP(A,2,2) OP(A,3,3) OP(A,4,4) OP(A,5,5) OP(A,6,6) OP(A,7,7) \
                     OP(A,8,8) OP(A,9,9) OP(A,10,a) OP(A,11,b) OP(A,12,c) OP(A,13,d) OP(A,14,e) OP(A,15,f)

// ---- cross-lane helpers -------------------------------------------------
#define ROR1 0x121
#define ROR2 0x122
#define ROR4 0x124
#define ROR8 0x128
#define BC15 0x142
#define BC31 0x143

template<int CTRL>
__device__ __forceinline__ double dpp_f64(double x) {
    union { double d; int i[2]; } a; a.d = x;
    union { int i[2]; double d; } r;
    r.i[0] = __builtin_amdgcn_update_dpp(a.i[0], a.i[0], CTRL, 0xF, 0xF, false);
    r.i[1] = __builtin_amdgcn_update_dpp(a.i[1], a.i[1], CTRL, 0xF, 0xF, false);
    return r.d;
}
template<int CTRL>
__device__ __forceinline__ int dpp_i32(int x) {
    return __builtin_amdgcn_update_dpp(x, x, CTRL, 0xF, 0xF, false);
}

__device__ __forceinline__ double readlane_f64(double x, int sl) {
    const int s = __builtin_amdgcn_readfirstlane(sl);
    union { double d; int i2[2]; } a; a.d = x;
    union { int i2[2]; double d; } r;
    r.i2[0] = __builtin_amdgcn_readlane(a.i2[0], s);
    r.i2[1] = __builtin_amdgcn_readlane(a.i2[1], s);
    return r.d;
}
__device__ __forceinline__ double readlane_f64c(double x, int sl) {  // const lane
    union { double d; int i2[2]; } a; a.d = x;
    union { int i2[2]; double d; } r;
    r.i2[0] = __builtin_amdgcn_readlane(a.i2[0], sl);
    r.i2[1] = __builtin_amdgcn_readlane(a.i2[1], sl);
    return r.d;
}
__device__ __forceinline__ float readlane_f32u(float x, int sl) {
    union { float f; int i; } a; a.f = x;
    union { int i; float f; } r;
    r.i = __builtin_amdgcn_readlane(a.i, __builtin_amdgcn_readfirstlane(sl));
    return r.f;
}
__device__ __forceinline__ int readlane_i32(int x, int sl) {
    return __builtin_amdgcn_readlane(x, __builtin_amdgcn_readfirstlane(sl));
}
__device__ __forceinline__ int readlane_i32c(int x, int sl) {
    return __builtin_amdgcn_readlane(x, sl);
}

// tree-select element s (uniform, 0..15) of a v16i held in registers
__device__ __forceinline__ int sel16v_i(v16i p, int s) {
    const int t0_0 = (s & 1) ? p.s1 : p.s0;
    const int t0_1 = (s & 1) ? p.s3 : p.s2;
    const int t0_2 = (s & 1) ? p.s5 : p.s4;
    const int t0_3 = (s & 1) ? p.s7 : p.s6;
    const int t0_4 = (s & 1) ? p.s9 : p.s8;
    const int t0_5 = (s & 1) ? p.sb : p.sa;
    const int t0_6 = (s & 1) ? p.sd : p.sc;
    const int t0_7 = (s & 1) ? p.sf : p.se;
    const int t1_0 = (s & 2) ? t0_1 : t0_0;
    const int t1_1 = (s & 2) ? t0_3 : t0_2;
    const int t1_2 = (s & 2) ? t0_5 : t0_4;
    const int t1_3 = (s & 2) ? t0_7 : t0_6;
    const int a0 = (s & 4) ? t1_1 : t1_0;
    const int a1 = (s & 4) ? t1_3 : t1_2;
    return (s & 8) ? a1 : a0;
}
__device__ __forceinline__ double sel16v_d(v16d p, int s) {
    const double t0_0 = (s & 1) ? p.s1 : p.s0;
    const double t0_1 = (s & 1) ? p.s3 : p.s2;
    const double t0_2 = (s & 1) ? p.s5 : p.s4;
    const double t0_3 = (s & 1) ? p.s7 : p.s6;
    const double t0_4 = (s & 1) ? p.s9 : p.s8;
    const double t0_5 = (s & 1) ? p.sb : p.sa;
    const double t0_6 = (s & 1) ? p.sd : p.sc;
    const double t0_7 = (s & 1) ? p.sf : p.se;
    const double t1_0 = (s & 2) ? t0_1 : t0_0;
    const double t1_1 = (s & 2) ? t0_3 : t0_2;
    const double t1_2 = (s & 2) ? t0_5 : t0_4;
    const double t1_3 = (s & 2) ? t0_7 : t0_6;
    const double a0 = (s & 4) ? t1_1 : t1_0;
    const double a1 = (s & 4) ? t1_3 : t1_2;
    return (s & 8) ? a1 : a0;
}

// Fused (value, index) min over 16 cand/lane x 64 lanes; ties -> smallest
// j = (k<<6)|l (np.argmin first-occurrence).
// R12: fmin TREE (depth 4, ILP) -> value-only f64 DPP min -> { ballot of
// tied lanes CONCURRENT WITH binary walk } -> if exactly one lane holds the
// min (generic case), one readlane from ctz(tied) replaces the 6-step i32
// key DPP chain (~70cy off the serial chain per call). Multi-lane tie
// (measure-zero on random data) falls back to the DPP key min -- result
// bit-identical: a lane's key uses its smallest tied k (walk prefers left
// subtree), so min over lanes of (kloc<<6|l) is the global smallest j.
// (R5's fused (v,key) combine was 6% slower; DST_ reorderings rejected:
// they change the reference's f64 rounding order.)
__device__ __forceinline__ void lexpair(v16d c, int l,
                                        double& gv_o, int& jm_o) {
    const double a0 = fmin(c.s0, c.s1), a1 = fmin(c.s2, c.s3),
                 a2 = fmin(c.s4, c.s5), a3 = fmin(c.s6, c.s7),
                 a4 = fmin(c.s8, c.s9), a5 = fmin(c.sa, c.sb),
                 a6 = fmin(c.sc, c.sd), a7 = fmin(c.se, c.sf);
    const double b0 = fmin(a0, a1), b1 = fmin(a2, a3),
                 b2 = fmin(a4, a5), b3 = fmin(a6, a7);
    const double d0 = fmin(b0, b1), d1 = fmin(b2, b3);
    const double vloc = fmin(d0, d1);
    double v = vloc;
#define VS_(C) { const double pv = dpp_f64<C>(v); v = fmin(pv, v); }
    VS_(ROR1) VS_(ROR2) VS_(ROR4) VS_(ROR8) VS_(BC15) VS_(BC31)
#undef VS_
    const double gv = readlane_f64c(v, 63);
    // ballot issues here; its result is consumed after the walk finishes,
    // so the two overlap on the chain.
    const unsigned long long tied = __ballot(vloc == gv);
    const int bit3 = (d0 == gv) ? 0 : 1;
    const double bsel = bit3 ? b2 : b0;
    const int bit2 = (bsel == gv) ? 0 : 1;
    const double asel = bit2 ? (bit3 ? a6 : a2) : (bit3 ? a4 : a0);
    const int bit1 = (asel == gv) ? 0 : 1;
    const double csel = bit1 ? (bit2 ? (bit3 ? c.se : c.s6) : (bit3 ? c.sa : c.s2))
                             : (bit2 ? (bit3 ? c.sc : c.s4) : (bit3 ? c.s8 : c.s0));
    const int bit0 = (csel == gv) ? 0 : 1;
    const int kloc = (bit3 << 3) | (bit2 << 2) | (bit1 << 1) | bit0;
    const int keyl = (kloc << 6) | l;
    if (__builtin_popcountll(tied) == 1) {   // wave-uniform branch (scalar)
        jm_o = readlane_i32(keyl, (int)__builtin_ctzll(tied));
    } else {
        int key = (vloc == gv) ? keyl : 0x7FFFFFFF;
#define KS_(C) { const int pk = dpp_i32<C>(key); key = (pk < key) ? pk : key; }
        KS_(ROR1) KS_(ROR2) KS_(ROR4) KS_(ROR8) KS_(BC15) KS_(BC31)
#undef KS_
        jm_o = readlane_i32c(key, 63);
    }
    gv_o = gv;
}

// K1: 512 blocks (16 jb-chunks x 32 batches). Builds transposed ct[b][i][j]
// (exact reference f32 arithmetic) AND per-row (best, second-best) over its
// 64-col chunk (strict <, ascending scan => first occurrence for both).
// NOTE (rounds 4/7/9): do NOT fuse this into the matcher launch. Serializing
// build onto 32 blocks costs ~60us (R4); flag-gated single-launch fusion is
// correct but the in-kernel produce->consume path is ~25us slower than the
// kernel-boundary path (R7/R9: dirty-L2 reads + whole-grid build tail),
// and cooperative launch breaks the harness's hipGraph capture (R8).
__global__ __launch_bounds__(256) void build_kernel(
    const float* __restrict__ obj, const float* __restrict__ cd,
    const float* __restrict__ gi, float* __restrict__ ct,
    float* __restrict__ pv, int* __restrict__ pj,
    float* __restrict__ pv2, int* __restrict__ pj2)
{
    __shared__ float tile[64][65];
    const int b  = blockIdx.y;
    const int jb = blockIdx.x << 6;
    const int t  = threadIdx.x;
    const float* objb = obj + (b << 10);
    const float4* cd4 = (const float4*)(cd + ((size_t)b << 16));
    const float4* gi4 = (const float4*)(gi + ((size_t)b << 16));

    #pragma unroll
    for (int p = 0; p < 4; ++p) {
        const int f  = t + (p << 8);
        const int jj = f >> 4;          // 0..63
        const int q  = f & 15;
        const int i0 = q << 2;          // 0,4,..,60
        const int j  = jb + jj;
        const float om = __fmul_rn(5.0f, -objb[j]);
        const float4 c4 = cd4[(j << 4) + q];
        const float4 q4 = gi4[(j << 4) + q];
        tile[i0 + 0][jj] = __fadd_rn(__fadd_rn(om, __fmul_rn(10.0f, c4.x)), __fmul_rn(2.0f, -q4.x));
        tile[i0 + 1][jj] = __fadd_rn(__fadd_rn(om, __fmul_rn(10.0f, c4.y)), __fmul_rn(2.0f, -q4.y));
        tile[i0 + 2][jj] = __fadd_rn(__fadd_rn(om, __fmul_rn(10.0f, c4.z)), __fmul_rn(2.0f, -q4.z));
        tile[i0 + 3][jj] = __fadd_rn(__fadd_rn(om, __fmul_rn(10.0f, c4.w)), __fmul_rn(2.0f, -q4.w));
    }
    __syncthreads();
    #pragma unroll
    for (int r = 0; r < 16; ++r) {      // coalesced ct write
        const int idx = (r << 8) + t;
        const int i = idx >> 6, j2 = idx & 63;
        ct[(((size_t)(b << 6) + i) << 10) + jb + j2] = tile[i][j2];
    }
    if (t < 64) {                        // (best, second) for row t
        float bv = tile[t][0]; int bc = 0;
        float sv = 1e30f;      int sc2 = 0;
        #pragma unroll 8
        for (int c = 1; c < 64; ++c) {
            const float v = tile[t][c];
            const bool t1 = v < bv;                 // new best (strict: first occ)
            const bool t2 = (!t1) && (v < sv);      // new second
            sv  = t1 ? bv : (t2 ? v : sv);
            sc2 = t1 ? bc : (t2 ? c : sc2);
            bv  = t1 ? v : bv;
            bc  = t1 ? c : bc;
        }
        const int o = (((b << 6) + t) << 4) + blockIdx.x;
        pv[o]  = bv;  pj[o]  = jb + bc;
        pv2[o] = sv;  pj2[o] = jb + sc2;
    }
}

// ---- matcher core (round-3 verified logic, loader-templated) -------------
// LDS-free JV matcher on one wave.
//  - row4col derived on demand: i = ctz(ballot(c4r_rep == jm)); assigned <=> mask!=0
//  - step-1: precomputed (best, second) + EXACT dirty marking; full row reload
//    only when BOTH best and second columns are dirty.
//  - u-update for SR rows via m_rec (shortest frozen at pop == minv then).
//  - c_cur prefetched unconditionally at loop top (R11).
// All per-lane state in ext_vectors with compile-time element access: NO
// alloca may exist (round-1 lesson: promote-alloca-to-LDS cost 40us).
// NEEDS ~80-120 VGPRs: never cap below that (round-7 lesson: a 64-VGPR cap
// spilled to scratch, WRITE_SIZE 256KB->11.7MB, matcher 68->160us).
template<class LR>
__device__ __forceinline__ void matcher_core(
    const int l, const int g, LR load_row,
    const float pre_v, const int pre_j, const float sec_v, const int sec_j,
    float* __restrict__ out_ind_b, float* __restrict__ out_mask_b)
{
    const double INF = __builtin_inf();
    double u_rep = 0.0;       // u[l]
    double m_rec = 0.0;       // minv at the pop that added row l to SR
    bool   inSR  = false;
    int    c4r_rep = -1;      // col4row[l]
    unsigned asg   = 0u;      // bit k: column l+64k assigned (output only)
    unsigned dirty = 0u;      // bit k: v of column l+64k STRICTLY changed
    v16d v_r, sh_r;
    v16i path;
    v16f c_cur, c_i;
#define INI_(K,H) { v_r.s##H = 0.0; sh_r.s##H = 0.0; path.s##H = 0; }
    REP16(INI_)
#undef INI_
#define Z16_(K,H) { c_cur.s##H = 0.0f; c_i.s##H = 0.0f; }
    REP16(Z16_)
#undef Z16_

    for (int cur = 0; cur < g; ++cur) {
        // ---- prefetch row cur (always in flight; consumed only on the
        // dirty-dirty recompute or the slow path) ----
        c_cur = load_row(cur);
        // ---- step-1 argmin ----
        const float pre_vc = readlane_f32u(pre_v, cur);
        int jm = readlane_i32(pre_j, cur);
        double minv = (double)pre_vc;
        {
            const int ow1 = jm & 63, sl1 = jm >> 6;
            const unsigned d1 = (unsigned)readlane_i32((int)dirty, ow1);
            if ((d1 >> sl1) & 1u) {
                // best column dirty -> try exact second-best resolution
                const float sv_c = readlane_f32u(sec_v, cur);
                const int   sj_c = readlane_i32(sec_j, cur);
                const unsigned d2 = (unsigned)readlane_i32((int)dirty, sj_c & 63);
                if (!((d2 >> (sj_c >> 6)) & 1u) && (sj_c != jm)) {
                    const double vpj = readlane_f64(sel16v_d(v_r, sl1), ow1);
                    const double vA = (double)pre_vc - vpj;   // exact: (f64)cost - v
                    const double vB = (double)sv_c;           // clean: v == 0
                    const bool tt = (vB < vA) || ((vB == vA) && (sj_c < jm));
                    minv = tt ? vB : vA;
                    jm   = tt ? sj_c : jm;
                } else {
                    v16d rr0;
#define RR0_(K,H) rr0.s##H = (double)c_cur.s##H - v_r.s##H;
                    REP16(RR0_)
#undef RR0_
                    lexpair(rr0, l, minv, jm);
                }
            }
        }
        const unsigned long long mk0 = __ballot(c4r_rep == jm);

        if (mk0 == 0ull) {
            // ---- fast row: O(1) bookkeeping (u,v of others unchanged) ----
            u_rep   = (l == cur) ? u_rep + minv : u_rep;
            c4r_rep = (l == cur) ? jm           : c4r_rep;
            asg     = (l == (jm & 63)) ? (asg | (1u << (jm >> 6))) : asg;
        } else {
            // ---- slow path: exact reference Dijkstra from step-1 state ----
            int i = (int)__builtin_ctzll(mk0);
            c_i = load_row(i);
            double ui = readlane_f64(u_rep, i);
            unsigned sc = (l == (jm & 63)) ? (1u << (jm >> 6)) : 0u;
            inSR  = (l == i);
            m_rec = minv;                            // valid only where inSR
#define SH0_(K,H) { sh_r.s##H = (double)c_cur.s##H - v_r.s##H; path.s##H = cur; }
            REP16(SH0_)
#undef SH0_

            int sink = -1;
            while (sink < 0) {
                v16d cand;
#define DST_(K,H) { const double rr = ((minv + (double)c_i.s##H) - ui) - v_r.s##H; \
                    const bool notSC = !((sc >> K) & 1u); \
                    const bool upd = notSC && (rr < sh_r.s##H); /* strict < */ \
                    sh_r.s##H = upd ? rr : sh_r.s##H; \
                    path.s##H = upd ? i : path.s##H; \
                    cand.s##H = notSC ? sh_r.s##H : INF; }
                REP16(DST_)
#undef DST_
                lexpair(cand, l, minv, jm);
                const unsigned long long mk = __ballot(c4r_rep == jm);
                if (l == (jm & 63)) sc |= (1u << (jm >> 6));
                if (mk == 0ull) {
                    sink = jm;
                } else {
                    i = (int)__builtin_ctzll(mk);
                    c_i = load_row(i);
                    if (l == i) { inSR = true; m_rec = minv; }
                    ui = readlane_f64(u_rep, i);
                }
            }

            // dual updates (reference order: u, then v, then augment).
            if (l == cur)       u_rep += minv;
            else if (inSR)      u_rep += minv - m_rec;
            unsigned chg = 0u;
#define VUP_(K,H) { const bool in_sc = (sc >> K) & 1u; \
                    const double nv = v_r.s##H - (minv - sh_r.s##H); \
                    chg = (in_sc && (sh_r.s##H != minv)) ? (chg | (1u << K)) : chg; \
                    v_r.s##H = in_sc ? nv : v_r.s##H; }
            REP16(VUP_)
#undef VUP_
            dirty |= chg;   // EXACT: only strictly-changed columns

            // augment along alternating path
            int j = sink;
            while (true) {
                const int so = j & 63, ss = j >> 6;
                const int ii = readlane_i32(sel16v_i(path, ss), so);
                const int nj = readlane_i32(c4r_rep, ii);   // old col4row[ii]
                asg     = (l == so) ? (asg | (1u << ss)) : asg;
                c4r_rep = (l == ii) ? j : c4r_rep;
                j = nj;
                if (ii == cur) break;
            }
        }
    }

    // ---- output: mask/zeros from asg bits; indices via one scatter ----
#define OUT_(K,H) { const int jj = l + (K << 6); const bool a_ = (asg >> K) & 1u; \
    out_mask_b[jj] = a_ ? 1.0f : 0.0f; \
    if (!a_) out_ind_b[jj] = 0.0f; }
    REP16(OUT_)
#undef OUT_
    if (c4r_rep >= 0) out_ind_b[c4r_rep] = (float)l;  // disjoint from zeros
}

// K2 (workspace path): 32 blocks x 256 threads. Wave 0 runs the matcher;
// waves 1-3 stream the batch's FIRST g ROWS of the ct slice (linear from
// row 0 = matcher's cur order) to pull them from LLC into THIS XCD's L2,
// then retire. L2 is cold at kernel start (kernel-boundary flush; round-5:
// FETCH identical under XCD-aligned grids); warming was +7.5us in round 6.
__global__ __launch_bounds__(256, 1) void matcher_ws(
    const int* __restrict__ ngt, const float* __restrict__ ct,
    const float* __restrict__ pv, const int* __restrict__ pj,
    const float* __restrict__ pv2, const int* __restrict__ pj2,
    float* __restrict__ out_ind, float* __restrict__ out_mask)
{
    const int b = blockIdx.x;
    const int t = threadIdx.x;
    const int g = ngt[b];
    const float* ctb = ct + ((size_t)(b << 6) << 10);

    if (t >= 64) {
        // ---- L2-warm waves: read-only sweep of rows 0..g-1, DCE-protected ----
        const float4* c4p = (const float4*)ctb;     // 256 float4 per row
        const int nmax = g << 8;                    // g * 256 float4s
        for (int n = t - 64; n < nmax; n += 192) {
            const float4 x = c4p[n];
            asm volatile("" :: "v"(x.x), "v"(x.y), "v"(x.z), "v"(x.w));
        }
        return;
    }

    const int l = t;

    // ---- per-row precomputed (best, second) -> lane l = row l ----
    const int base = ((b << 6) + l) << 4;
    const float4* pvq = (const float4*)(pv  + base);
    const int4*   pjq = (const int4*)(pj  + base);
    const float4* svq = (const float4*)(pv2 + base);
    const int4*   sjq = (const int4*)(pj2 + base);
    const float4 pA = pvq[0], pB = pvq[1], pC = pvq[2], pD = pvq[3];
    const int4   jA = pjq[0], jB = pjq[1], jC = pjq[2], jD = pjq[3];
    const float4 sA = svq[0], sB = svq[1], sC = svq[2], sD = svq[3];
    const int4   tA = sjq[0], tB = sjq[1], tC = sjq[2], tD = sjq[3];
    float bv = pA.x; int bj = jA.x; float sv = sA.x; int sj = tA.x;
    // merge chunks ascending; (best, second) both first-occurrence exact
#define MERGE_(CV,CJ,C2V,C2J) { const bool nb = (CV) < bv; \
    const bool s1 = (C2V) < bv; const bool s2 = (CV) < sv; \
    const float nsv = nb ? (s1 ? (C2V) : bv) : (s2 ? (CV) : sv); \
    const int   nsj = nb ? (s1 ? (C2J) : bj) : (s2 ? (CJ) : sj); \
    bj = nb ? (CJ) : bj; bv = nb ? (CV) : bv; sv = nsv; sj = nsj; }
    MERGE_(pA.y,jA.y,sA.y,tA.y) MERGE_(pA.z,jA.z,sA.z,tA.z) MERGE_(pA.w,jA.w,sA.w,tA.w)
    MERGE_(pB.x,jB.x,sB.x,tB.x) MERGE_(pB.y,jB.y,sB.y,tB.y) MERGE_(pB.z,jB.z,sB.z,tB.z) MERGE_(pB.w,jB.w,sB.w,tB.w)
    MERGE_(pC.x,jC.x,sC.x,tC.x) MERGE_(pC.y,jC.y,sC.y,tC.y) MERGE_(pC.z,jC.z,sC.z,tC.z) MERGE_(pC.w,jC.w,sC.w,tC.w)
    MERGE_(pD.x,jD.x,sD.x,tD.x) MERGE_(pD.y,jD.y,sD.y,tD.y) MERGE_(pD.z,jD.z,sD.z,tD.z) MERGE_(pD.w,jD.w,sD.w,tD.w)
#undef MERGE_

    auto load_row = [&](int ri) -> v16f {
        v16f d; const float* rp_ = ctb + ((size_t)ri << 10) + l;
#define LDW_(D,K,H) D.s##H = rp_[(K) << 6];
        REP16A(LDW_, d)
#undef LDW_
        return d;
    };
    matcher_core(l, g, load_row, bv, bj, sv, sj,
                 out_ind + (b << 10), out_mask + (b << 10));
}

// ---- no-workspace fallback: compute rows on the fly ----------------------
__global__ __launch_bounds__(64, 1) void matcher_nws(
    const float* __restrict__ obj, const float* __restrict__ cd,
    const float* __restrict__ gi, const int* __restrict__ ngt,
    float* __restrict__ out_ind, float* __restrict__ out_mask)
{
    const int b = blockIdx.x;
    const int l = threadIdx.x;
    const int g = ngt[b];
    const float* objb = obj + (b << 10);
    const float* cdb  = cd + ((size_t)b << 16);
    const float* gib  = gi + ((size_t)b << 16);

    v16f objm;
#define OBJI_(K,H) objm.s##H = __fmul_rn(5.0f, -objb[l + (K << 6)]);
    REP16(OBJI_)
#undef OBJI_
    auto load_row = [&](int ri) -> v16f {
        v16f d;
#define LDN_(D,K,H) { const int idx_ = ((l + ((K) << 6)) << 6) + ri; \
    D.s##H = __fadd_rn(__fadd_rn(objm.s##H, __fmul_rn(10.0f, cdb[idx_])), \
                       __fmul_rn(2.0f, -gib[idx_])); }
        REP16A(LDN_, d)
#undef LDN_
        return d;
    };

    float pre_v = 0.0f; int pre_j = 0;
    for (int i = 0; i < g; ++i) {            // cooperative per-row argmin
        v16f c = load_row(i);
        v16d c64;
#define CV_(K,H) c64.s##H = (double)c.s##H;
        REP16(CV_)
#undef CV_
        double gv; int j0;
        lexpair(c64, l, gv, j0);
        pre_v = (l == i) ? (float)gv : pre_v;
        pre_j = (l == i) ? j0 : pre_j;
    }
    // sec == pre: dirty best -> sec also dirty (same col) -> full recompute
    matcher_core(l, g, load_row, pre_v, pre_j, pre_v, pre_j,
                 out_ind + (b << 10), out_mask + (b << 10));
}

extern "C" void kernel_launch(void* const* d_in, const int* in_sizes, int n_in,
                              void* d_out, int out_size, void* d_ws, size_t ws_size,
                              hipStream_t stream)
{
    const float* obj = (const float*)d_in[1];
    const float* cd  = (const float*)d_in[2];
    const float* gi  = (const float*)d_in[3];
    const int*   ngt = (const int*)d_in[4];
    float* out0 = (float*)d_out;
    float* out1 = out0 + B_ * Q_;

    const size_t ct_b = (size_t)B_ * G_ * Q_ * sizeof(float);       // 8 MB
    const size_t pv_b = (size_t)B_ * G_ * 16 * sizeof(float);       // 128 KB
    if (ws_size >= ct_b + 4 * pv_b) {
        float* ct  = (float*)d_ws;
        float* pv  = (float*)((char*)d_ws + ct_b);
        int*   pj  = (int*)  ((char*)d_ws + ct_b + pv_b);
        float* pv2 = (float*)((char*)d_ws + ct_b + 2 * pv_b);
        int*   pj2 = (int*)  ((char*)d_ws + ct_b + 3 * pv_b);
        build_kernel<<<dim3(16, B_), 256, 0, stream>>>(obj, cd, gi, ct, pv, pj, pv2, pj2);
        matcher_ws<<<B_, 256, 0, stream>>>(ngt, ct, pv, pj, pv2, pj2, out0, out1);
    } else {
        matcher_nws<<<B_, 64, 0, stream>>>(obj, cd, gi, ngt, out0, out1);
    }
}